// Round 11
// baseline (370.678 us; speedup 1.0000x reference)
//
#include <hip/hip_runtime.h>
#include <hip/hip_bf16.h>

#define GG 128      // num_graphs (static in problem)
#define BSHIFT 9    // 512 nodes per bucket
#define BMASK 511
#define BNODES 512
#define PADI 16     // ints per padded global bucket counter (one 64B line each)
#define CAP 8192    // bucket capacity (mean ~5100 at n=100k,e=1M)
#define NPL 4       // feature planes
#define PD 16       // dims per plane

typedef __attribute__((ext_vector_type(8))) short bf16x8;
typedef __attribute__((ext_vector_type(4))) float f32x4;
typedef __attribute__((ext_vector_type(4))) unsigned short us4;

// ---------------- bf16 helpers (RNE) ----------------
__device__ __forceinline__ ushort f2bf(float f) {
    union { float f; unsigned u; } v; v.f = f;
    unsigned r = v.u + 0x7FFF + ((v.u >> 16) & 1);
    return (ushort)(r >> 16);
}
__device__ __forceinline__ float bf2f(ushort s) {
    union { unsigned u; float f; } v; v.u = ((unsigned)s) << 16;
    return v.f;
}

// ------- f32 row-major -> bf16 plane-major [q][n][16] ------------------------
__global__ __launch_bounds__(256) void to_bf16_pl(const float* __restrict__ X,
                                                  ushort* __restrict__ Xb, int n) {
    int i = blockIdx.x * 256 + threadIdx.x;
    if (i >= n * 16) return;
    int node = i >> 4, c4 = i & 15;
    float4 v = *reinterpret_cast<const float4*>(X + (size_t)node * 64 + c4 * 4);
    ushort4 o;
    o.x = f2bf(v.x); o.y = f2bf(v.y); o.z = f2bf(v.z); o.w = f2bf(v.w);
    int q = c4 >> 2, pos = (c4 & 3) * 4;
    *reinterpret_cast<ushort4*>(Xb + ((size_t)q * n + node) * PD + pos) = o;
}

// ------- phase A: bucket edges by coarse key (both directions) --------------
__global__ __launch_bounds__(256) void bucket_scatter(
    const int* __restrict__ ei,
    int* __restrict__ gcurF, int* __restrict__ gcurB,
    int2* __restrict__ bktF, int2* __restrict__ bktB,
    int e, int nb) {
    extern __shared__ int lds[];             // cntF[nb], cntB[nb]
    int* cntF = lds;
    int* cntB = lds + nb;
    int t = threadIdx.x;
    for (int i = t; i < 2 * nb; i += 256) lds[i] = 0;
    __syncthreads();
    int base = blockIdx.x * 2048;
    int s[8], d[8], rf[8], rb[8];
#pragma unroll
    for (int k = 0; k < 8; k++) {
        int idx = base + k * 256 + t;
        if (idx < e) {
            s[k] = ei[idx];
            d[k] = ei[e + idx];
            rf[k] = atomicAdd(&cntF[d[k] >> BSHIFT], 1);
            rb[k] = atomicAdd(&cntB[s[k] >> BSHIFT], 1);
        }
    }
    __syncthreads();
    for (int c = t; c < nb; c += 256) {
        int vF = cntF[c];
        if (vF) cntF[c] = atomicAdd(&gcurF[(size_t)c * PADI], vF);
        int vB = cntB[c];
        if (vB) cntB[c] = atomicAdd(&gcurB[(size_t)c * PADI], vB);
    }
    __syncthreads();
#pragma unroll
    for (int k = 0; k < 8; k++) {
        int idx = base + k * 256 + t;
        if (idx < e) {
            int cF = d[k] >> BSHIFT;
            int slotF = cntF[cF] + rf[k];
            if (slotF < CAP) bktF[(size_t)cF * CAP + slotF] = make_int2(s[k], d[k]);
            int cB = s[k] >> BSHIFT;
            int slotB = cntB[cB] + rb[k];
            if (slotB < CAP) bktB[(size_t)cB * CAP + slotB] = make_int2(d[k], s[k]);
        }
    }
}

// ------- scan bucket sizes -> bucket bases (nb <= 256) ----------------------
__global__ __launch_bounds__(256) void bucket_scan(
    const int* __restrict__ gcurF, const int* __restrict__ gcurB,
    int* __restrict__ gbaseF, int* __restrict__ gbaseB,
    int* __restrict__ off_f, int* __restrict__ off_b,
    int nb, int n, int e) {
    const int* gcur = blockIdx.x ? gcurB : gcurF;
    int* gbase = blockIdx.x ? gbaseB : gbaseF;
    int* off = blockIdx.x ? off_b : off_f;
    __shared__ int sc[2][256];
    int t = threadIdx.x;
    int v = (t < nb) ? min(gcur[(size_t)t * PADI], CAP) : 0;
    sc[0][t] = v;
    __syncthreads();
    int pp = 0;
    for (int ofs = 1; ofs < 256; ofs <<= 1) {
        int u = sc[pp][t];
        if (t >= ofs) u += sc[pp][t - ofs];
        sc[pp ^ 1][t] = u;
        __syncthreads();
        pp ^= 1;
    }
    if (t < nb) gbase[t] = sc[pp][t] - v;    // exclusive
    if (t == 0) { gbase[nb] = e; off[n] = e; }
}

// ------- phase B: per-bucket CSR finalize (one block per bucket) ------------
__global__ __launch_bounds__(256) void bucket_csr(
    const int2* __restrict__ bkt, const int* __restrict__ gcur,
    const int* __restrict__ gbase,
    int* __restrict__ csr, int* __restrict__ off, float* __restrict__ inv,
    int n, int nb) {
    __shared__ int cnt[BNODES];
    __shared__ int cur[BNODES];
    __shared__ int sc[2][BNODES];
    int c = blockIdx.x;
    int t = threadIdx.x;
    int size = gcur[(size_t)c * PADI];
    if (size > CAP) size = CAP;
    const int2* src = bkt + (size_t)c * CAP;
    for (int l = t; l < BNODES; l += 256) cnt[l] = 0;
    __syncthreads();
    for (int i = t; i < size; i += 256)
        atomicAdd(&cnt[src[i].y & BMASK], 1);
    __syncthreads();
    for (int l = t; l < BNODES; l += 256) sc[0][l] = cnt[l];
    __syncthreads();
    int pp = 0;
    for (int ofs = 1; ofs < BNODES; ofs <<= 1) {
        for (int l = t; l < BNODES; l += 256) {
            int u = sc[pp][l];
            if (l >= ofs) u += sc[pp][l - ofs];
            sc[pp ^ 1][l] = u;
        }
        __syncthreads();
        pp ^= 1;
    }
    int gb = gbase[c];
    for (int l = t; l < BNODES; l += 256) {
        int excl = sc[pp][l] - cnt[l];
        cur[l] = excl;
        int node = c * BNODES + l;
        if (node < n) {
            off[node] = gb + excl;
            inv[node] = 1.f / fmaxf((float)cnt[l], 1.f);
        }
    }
    __syncthreads();
    for (int i = t; i < size; i += 256) {
        int2 vk = src[i];
        int slot = atomicAdd(&cur[vk.y & BMASK], 1);
        csr[gb + slot] = vk.x;
    }
}

// ---- gather-mean over ONE 16-dim plane (both directions) -------------------
// 8 threads/node: 2 dirs x 4 lanes x ushort4. Plane = 3.2 MB -> per-XCD L2.
// csr loads + agg stores are NON-TEMPORAL so streams don't evict the plane.
__global__ __launch_bounds__(256) void gather_mean_pl(
    const ushort* __restrict__ Xp,
    const int* __restrict__ off_f, const int* __restrict__ csr_f,
    const float* __restrict__ invf,
    const int* __restrict__ off_b, const int* __restrict__ csr_b,
    const float* __restrict__ invb,
    ushort* __restrict__ aggfp, ushort* __restrict__ aggbp, int n) {
    int tid = blockIdx.x * 256 + threadIdx.x;
    int node = tid >> 3;
    if (node >= n) return;
    int sub = tid & 7;
    int dir = sub >> 2;
    int c = (sub & 3) * 4;
    const int* off = dir ? off_b : off_f;
    const int* csr = dir ? csr_b : csr_f;
    const float* inv = dir ? invb : invf;
    ushort* agg = dir ? aggbp : aggfp;

    int b = off[node], en = off[node + 1];
    float ax = 0.f, ay = 0.f, az = 0.f, aw = 0.f;
    int k = b;
    for (; k + 3 < en; k += 4) {
        int n0 = __builtin_nontemporal_load(csr + k);
        int n1 = __builtin_nontemporal_load(csr + k + 1);
        int n2 = __builtin_nontemporal_load(csr + k + 2);
        int n3 = __builtin_nontemporal_load(csr + k + 3);
        ushort4 v0 = *reinterpret_cast<const ushort4*>(Xp + (size_t)n0 * PD + c);
        ushort4 v1 = *reinterpret_cast<const ushort4*>(Xp + (size_t)n1 * PD + c);
        ushort4 v2 = *reinterpret_cast<const ushort4*>(Xp + (size_t)n2 * PD + c);
        ushort4 v3 = *reinterpret_cast<const ushort4*>(Xp + (size_t)n3 * PD + c);
        ax += bf2f(v0.x) + bf2f(v1.x) + bf2f(v2.x) + bf2f(v3.x);
        ay += bf2f(v0.y) + bf2f(v1.y) + bf2f(v2.y) + bf2f(v3.y);
        az += bf2f(v0.z) + bf2f(v1.z) + bf2f(v2.z) + bf2f(v3.z);
        aw += bf2f(v0.w) + bf2f(v1.w) + bf2f(v2.w) + bf2f(v3.w);
    }
    for (; k < en; k++) {
        int s = __builtin_nontemporal_load(csr + k);
        ushort4 v = *reinterpret_cast<const ushort4*>(Xp + (size_t)s * PD + c);
        ax += bf2f(v.x); ay += bf2f(v.y); az += bf2f(v.z); aw += bf2f(v.w);
    }
    float iv = inv[node];
    us4 r;
    r.x = f2bf(ax * iv); r.y = f2bf(ay * iv); r.z = f2bf(az * iv); r.w = f2bf(aw * iv);
    __builtin_nontemporal_store(r, reinterpret_cast<us4*>(agg + (size_t)node * PD + c));
}

// ---------------- fused bidirectional SAGE layer (MFMA bf16, plane I/O) -----
// out_bf = relu(0.5*(aggf@Wlf^T + aggb@Wlb^T + xb@(Wrf+Wrb)^T) + 0.5*(blf+blb))
// Fragment layouts (m89-verified family):
//   A[m][k]: m=lane&15, k=(lane>>4)*8+j   B[k][j]: k=(lane>>4)*8+j, j=lane&15
//   D[m][j]: m=(lane>>4)*4+reg, j=lane&15
__global__ __launch_bounds__(256) void fused_sage_mfma(
    const ushort* __restrict__ Xb,
    const ushort* __restrict__ aggf, const ushort* __restrict__ aggb,
    const float* __restrict__ Wlf, const float* __restrict__ blf,
    const float* __restrict__ Wrf,
    const float* __restrict__ Wlb, const float* __restrict__ blb,
    const float* __restrict__ Wrb,
    ushort* __restrict__ OutB, int n)
{
    __shared__ ushort sA[64][72];       // +8 bf16 pad
    __shared__ ushort sW[3][64][72];    // bf16 weights, W[j][k] layout
    __shared__ float  sBias[64];
    const int t = threadIdx.x;
    const int base = blockIdx.x * 64;
    const int lane = t & 63;
    const int m0 = (t >> 6) * 16;       // wave's row offset
    const int lr = lane & 15;
    const int kb = lane >> 4;

    // ---- stage weights (bf16) + bias, once ----
#pragma unroll
    for (int i = 0; i < 4; i++) {
        int idx4 = t + 256 * i;               // 1024 float4s = 64x64
        int row = idx4 >> 4, c4 = idx4 & 15;
        float4 w0 = *reinterpret_cast<const float4*>(Wlf + row * 64 + c4 * 4);
        float4 w1 = *reinterpret_cast<const float4*>(Wlb + row * 64 + c4 * 4);
        float4 wa = *reinterpret_cast<const float4*>(Wrf + row * 64 + c4 * 4);
        float4 wb = *reinterpret_cast<const float4*>(Wrb + row * 64 + c4 * 4);
        ushort4 o;
        o.x = f2bf(w0.x); o.y = f2bf(w0.y); o.z = f2bf(w0.z); o.w = f2bf(w0.w);
        *reinterpret_cast<ushort4*>(&sW[0][row][c4 * 4]) = o;
        o.x = f2bf(w1.x); o.y = f2bf(w1.y); o.z = f2bf(w1.z); o.w = f2bf(w1.w);
        *reinterpret_cast<ushort4*>(&sW[1][row][c4 * 4]) = o;
        o.x = f2bf(wa.x + wb.x); o.y = f2bf(wa.y + wb.y);
        o.z = f2bf(wa.z + wb.z); o.w = f2bf(wa.w + wb.w);
        *reinterpret_cast<ushort4*>(&sW[2][row][c4 * 4]) = o;
    }
    if (t < 64) sBias[t] = 0.5f * (blf[t] + blb[t]);

    f32x4 acc0 = {0.f, 0.f, 0.f, 0.f};
    f32x4 acc1 = {0.f, 0.f, 0.f, 0.f};
    f32x4 acc2 = {0.f, 0.f, 0.f, 0.f};
    f32x4 acc3 = {0.f, 0.f, 0.f, 0.f};

    for (int p = 0; p < 3; p++) {
        const ushort* src = (p == 0) ? aggf : (p == 1) ? aggb : Xb;  // plane-major
        __syncthreads();
        // ---- stage A tile from 4 planes: 512 x 16B chunks ----
#pragma unroll
        for (int i = 0; i < 2; i++) {
            int c8 = t + 256 * i;             // 0..511
            int row = c8 >> 3;
            int q = (c8 >> 1) & 3;
            int h = (c8 & 1) * 8;
            int node = base + row;
            uint4 v = make_uint4(0u, 0u, 0u, 0u);
            if (node < n)
                v = *reinterpret_cast<const uint4*>(src + ((size_t)q * n + node) * PD + h);
            *reinterpret_cast<uint4*>(&sA[row][q * 16 + h]) = v;
        }
        __syncthreads();
        // ---- MFMA: 2 k-halves x 4 col-blocks ----
#pragma unroll
        for (int kh = 0; kh < 2; kh++) {
            bf16x8 a = *(const bf16x8*)(&sA[m0 + lr][kh * 32 + kb * 8]);
            bf16x8 b0 = *(const bf16x8*)(&sW[p][0 * 16 + lr][kh * 32 + kb * 8]);
            bf16x8 b1 = *(const bf16x8*)(&sW[p][1 * 16 + lr][kh * 32 + kb * 8]);
            bf16x8 b2 = *(const bf16x8*)(&sW[p][2 * 16 + lr][kh * 32 + kb * 8]);
            bf16x8 b3 = *(const bf16x8*)(&sW[p][3 * 16 + lr][kh * 32 + kb * 8]);
            acc0 = __builtin_amdgcn_mfma_f32_16x16x32_bf16(a, b0, acc0, 0, 0, 0);
            acc1 = __builtin_amdgcn_mfma_f32_16x16x32_bf16(a, b1, acc1, 0, 0, 0);
            acc2 = __builtin_amdgcn_mfma_f32_16x16x32_bf16(a, b2, acc2, 0, 0, 0);
            acc3 = __builtin_amdgcn_mfma_f32_16x16x32_bf16(a, b3, acc3, 0, 0, 0);
        }
    }
    // ---- epilogue: bias + relu + bf16 plane store ----
#pragma unroll
    for (int b = 0; b < 4; b++) {
        int j = lr + 16 * b;
        float bias = sBias[j];
        f32x4 ac = (b == 0) ? acc0 : (b == 1) ? acc1 : (b == 2) ? acc2 : acc3;
#pragma unroll
        for (int i = 0; i < 4; i++) {
            int row = base + m0 + kb * 4 + i;
            if (row < n) {
                float v = 0.5f * ac[i] + bias;
                v = v > 0.f ? v : 0.f;
                OutB[((size_t)(j >> 4) * n + row) * PD + (j & 15)] = f2bf(v);
            }
        }
    }
}

// ---- pooling: plane-coalesced, register accumulate, flush on graph change --
// 4 threads/node (ushort4 per plane, 4 planes unrolled). 16-lane group reads
// 128B contiguous per plane.
__global__ __launch_bounds__(256) void pool_partial(const ushort* __restrict__ H,
                                                    const int* __restrict__ batch,
                                                    float* __restrict__ psum,
                                                    float* __restrict__ pcnt, int n) {
    __shared__ float ls[GG * 64];
    __shared__ float lc[GG];
    int t = threadIdx.x;
    for (int i = t; i < GG * 64; i += 256) ls[i] = 0.f;
    for (int i = t; i < GG; i += 256) lc[i] = 0.f;
    __syncthreads();
    int chunk = (n + gridDim.x - 1) / gridDim.x;
    int base = blockIdx.x * chunk;
    int end = base + chunk; if (end > n) end = n;
    int nr = t >> 2;          // node offset 0..63
    int c  = (t & 3) * 4;     // dim chunk within plane

    float4 acc[4];
#pragma unroll
    for (int q = 0; q < 4; q++) acc[q] = make_float4(0.f, 0.f, 0.f, 0.f);
    int cnt = 0; int curg = -1;

#define POOL_FLUSH() do { if (curg >= 0) {                                   \
        _Pragma("unroll")                                                    \
        for (int q = 0; q < 4; q++) {                                        \
            atomicAdd(&ls[curg * 64 + q * 16 + c + 0], acc[q].x);            \
            atomicAdd(&ls[curg * 64 + q * 16 + c + 1], acc[q].y);            \
            atomicAdd(&ls[curg * 64 + q * 16 + c + 2], acc[q].z);            \
            atomicAdd(&ls[curg * 64 + q * 16 + c + 3], acc[q].w);            \
        }                                                                    \
        if ((t & 3) == 0) atomicAdd(&lc[curg], (float)cnt); } } while (0)

    for (int node = base + nr; node < end; node += 64) {
        int g = batch[node];
        if (g != curg) {
            POOL_FLUSH();
            curg = g; cnt = 0;
#pragma unroll
            for (int q = 0; q < 4; q++) acc[q] = make_float4(0.f, 0.f, 0.f, 0.f);
        }
#pragma unroll
        for (int q = 0; q < 4; q++) {
            ushort4 v = *reinterpret_cast<const ushort4*>(H + ((size_t)q * n + node) * PD + c);
            acc[q].x += bf2f(v.x); acc[q].y += bf2f(v.y);
            acc[q].z += bf2f(v.z); acc[q].w += bf2f(v.w);
        }
        cnt++;
    }
    POOL_FLUSH();
#undef POOL_FLUSH
    __syncthreads();
    for (int i = t; i < GG * 64; i += 256) {
        float v = ls[i];
        if (v != 0.f) atomicAdd(&psum[i], v);
    }
    for (int i = t; i < GG; i += 256) {
        float v = lc[i];
        if (v != 0.f) atomicAdd(&pcnt[i], v);
    }
}

// ---------------- head ----------------
__global__ __launch_bounds__(256) void pool_final(const float* __restrict__ psum,
                                                  const float* __restrict__ pcnt,
                                                  const float* __restrict__ PW,
                                                  const float* __restrict__ Pb,
                                                  float* __restrict__ out) {
    int t = blockIdx.x * 256 + threadIdx.x;
    int g = t >> 4, o = t & 15;
    if (g >= GG) return;
    float inv = 1.f / fmaxf(pcnt[g], 1.f);
    float acc = 0.f;
#pragma unroll 8
    for (int k = 0; k < 64; k++) acc += psum[g * 64 + k] * PW[o * 64 + k];
    out[t] = acc * inv + Pb[o];
}

extern "C" void kernel_launch(void* const* d_in, const int* in_sizes, int n_in,
                              void* d_out, int out_size, void* d_ws, size_t ws_size,
                              hipStream_t stream) {
    const float* x      = (const float*)d_in[0];
    const int*   ei     = (const int*)d_in[1];
    const int*   batch  = (const int*)d_in[2];
    const float* l0f_Wl = (const float*)d_in[4];
    const float* l0f_bl = (const float*)d_in[5];
    const float* l0f_Wr = (const float*)d_in[6];
    const float* l0b_Wl = (const float*)d_in[7];
    const float* l0b_bl = (const float*)d_in[8];
    const float* l0b_Wr = (const float*)d_in[9];
    const float* l1f_Wl = (const float*)d_in[10];
    const float* l1f_bl = (const float*)d_in[11];
    const float* l1f_Wr = (const float*)d_in[12];
    const float* l1b_Wl = (const float*)d_in[13];
    const float* l1b_bl = (const float*)d_in[14];
    const float* l1b_Wr = (const float*)d_in[15];
    const float* pred_W = (const float*)d_in[16];
    const float* pred_b = (const float*)d_in[17];

    const int n = in_sizes[0] / 64;
    const int e = in_sizes[1] / 2;
    const int nb = (n + BNODES - 1) >> BSHIFT;   // <= 256 required
    const size_t npl = (size_t)n * PD;           // elements per plane

    // ---- workspace layout (int elements) ----
    int* ws = (int*)d_ws;
    size_t o = 0;
    int*   gcurF = ws + o;  o += (size_t)nb * PADI;      // zeroed
    int*   gcurB = ws + o;  o += (size_t)nb * PADI;      // zeroed
    float* psum  = (float*)(ws + o); o += GG * 64;       // zeroed
    float* pcnt  = (float*)(ws + o); o += GG;            // zeroed
    size_t zcount = o;
    int*   gbaseF = ws + o; o += nb + 1;
    int*   gbaseB = ws + o; o += nb + 1;
    int*   off_f = ws + o;  o += n + 1;
    int*   off_b = ws + o;  o += n + 1;
    float* invf  = (float*)(ws + o); o += n;
    float* invb  = (float*)(ws + o); o += n;
    int*   csr_f = ws + o;  o += e;
    int*   csr_b = ws + o;  o += e;
    o = (o + 3) & ~(size_t)3;
    int2*  bktF  = (int2*)(ws + o); o += 2 * (size_t)nb * CAP;
    int2*  bktB  = (int2*)(ws + o); o += 2 * (size_t)nb * CAP;
    ushort* xb    = (ushort*)(ws + o); o += (size_t)n * 32;  // 4 planes (x->h0->h1)
    ushort* aggfb = (ushort*)(ws + o); o += (size_t)n * 32;  // 4 planes
    ushort* aggbb = (ushort*)(ws + o); o += (size_t)n * 32;  // 4 planes

    hipMemsetAsync(ws, 0, zcount * sizeof(int), stream);

    // ---- CSR build via bucket counting-sort ----
    to_bf16_pl<<<((size_t)n * 16 + 255) / 256, 256, 0, stream>>>(x, xb, n);
    bucket_scatter<<<(e + 2047) / 2048, 256, 2 * nb * sizeof(int), stream>>>(
        ei, gcurF, gcurB, bktF, bktB, e, nb);
    bucket_scan<<<2, 256, 0, stream>>>(gcurF, gcurB, gbaseF, gbaseB,
                                       off_f, off_b, nb, n, e);
    bucket_csr<<<nb, 256, 0, stream>>>(bktF, gcurF, gbaseF, csr_f, off_f, invf, n, nb);
    bucket_csr<<<nb, 256, 0, stream>>>(bktB, gcurB, gbaseB, csr_b, off_b, invb, n, nb);

    const int ggrid = ((size_t)n * 8 + 255) / 256;

    // layer 0: per-plane gather (L2-resident + nt streams), MFMA sage (in place)
    for (int q = 0; q < NPL; q++)
        gather_mean_pl<<<ggrid, 256, 0, stream>>>(
            xb + q * npl, off_f, csr_f, invf, off_b, csr_b, invb,
            aggfb + q * npl, aggbb + q * npl, n);
    fused_sage_mfma<<<(n + 63) / 64, 256, 0, stream>>>(xb, aggfb, aggbb,
        l0f_Wl, l0f_bl, l0f_Wr, l0b_Wl, l0b_bl, l0b_Wr, xb, n);

    // layer 1
    for (int q = 0; q < NPL; q++)
        gather_mean_pl<<<ggrid, 256, 0, stream>>>(
            xb + q * npl, off_f, csr_f, invf, off_b, csr_b, invb,
            aggfb + q * npl, aggbb + q * npl, n);
    fused_sage_mfma<<<(n + 63) / 64, 256, 0, stream>>>(xb, aggfb, aggbb,
        l1f_Wl, l1f_bl, l1f_Wr, l1b_Wl, l1b_bl, l1b_Wr, xb, n);

    // pooling + head
    pool_partial<<<256, 256, 0, stream>>>(xb, batch, psum, pcnt, n);
    pool_final<<<8, 256, 0, stream>>>(psum, pcnt, pred_W, pred_b, (float*)d_out);
}

// Round 13
// 366.046 us; speedup vs baseline: 1.0127x; 1.0127x over previous
//
#include <hip/hip_runtime.h>
#include <hip/hip_bf16.h>

#define GG 128      // num_graphs (static in problem)
#define BSHIFT 9    // 512 nodes per bucket
#define BMASK 511
#define BNODES 512
#define PADI 16     // ints per padded global bucket counter (one 64B line each)
#define CAP 8192    // bucket capacity (mean ~5100 at n=100k,e=1M)
#define NPL 4       // feature planes
#define PD 16       // dims per plane

typedef __attribute__((ext_vector_type(8))) short bf16x8;
typedef __attribute__((ext_vector_type(4))) float f32x4;
typedef __attribute__((ext_vector_type(4))) unsigned short us4;
typedef __attribute__((ext_vector_type(4))) int i32x4;

// ---------------- bf16 helpers (RNE) ----------------
__device__ __forceinline__ ushort f2bf(float f) {
    union { float f; unsigned u; } v; v.f = f;
    unsigned r = v.u + 0x7FFF + ((v.u >> 16) & 1);
    return (ushort)(r >> 16);
}
__device__ __forceinline__ float bf2f(ushort s) {
    union { unsigned u; float f; } v; v.u = ((unsigned)s) << 16;
    return v.f;
}

// ------- f32 row-major -> bf16 plane-major [q][n][16] ------------------------
__global__ __launch_bounds__(256) void to_bf16_pl(const float* __restrict__ X,
                                                  ushort* __restrict__ Xb, int n) {
    int i = blockIdx.x * 256 + threadIdx.x;
    if (i >= n * 16) return;
    int node = i >> 4, c4 = i & 15;
    float4 v = *reinterpret_cast<const float4*>(X + (size_t)node * 64 + c4 * 4);
    ushort4 o;
    o.x = f2bf(v.x); o.y = f2bf(v.y); o.z = f2bf(v.z); o.w = f2bf(v.w);
    int q = c4 >> 2, pos = (c4 & 3) * 4;
    *reinterpret_cast<ushort4*>(Xb + ((size_t)q * n + node) * PD + pos) = o;
}

// ------- phase A: bucket edges by coarse key, PACKED entries ----------------
// entry = (neighbor_value << 9) | (key & 511); value < 2^17 (n <= 131072)
__global__ __launch_bounds__(256) void bucket_scatter(
    const int* __restrict__ ei,
    int* __restrict__ gcurF, int* __restrict__ gcurB,
    int* __restrict__ bktF, int* __restrict__ bktB,
    int e, int nb) {
    extern __shared__ int lds[];             // cntF[nb], cntB[nb]
    int* cntF = lds;
    int* cntB = lds + nb;
    int t = threadIdx.x;
    for (int i = t; i < 2 * nb; i += 256) lds[i] = 0;
    __syncthreads();
    int base = blockIdx.x * 2048;
    int s[8], d[8], rf[8], rb[8];
#pragma unroll
    for (int k = 0; k < 8; k++) {
        int idx = base + k * 256 + t;
        if (idx < e) {
            s[k] = ei[idx];
            d[k] = ei[e + idx];
            rf[k] = atomicAdd(&cntF[d[k] >> BSHIFT], 1);
            rb[k] = atomicAdd(&cntB[s[k] >> BSHIFT], 1);
        }
    }
    __syncthreads();
    for (int c = t; c < nb; c += 256) {
        int vF = cntF[c];
        if (vF) cntF[c] = atomicAdd(&gcurF[(size_t)c * PADI], vF);
        int vB = cntB[c];
        if (vB) cntB[c] = atomicAdd(&gcurB[(size_t)c * PADI], vB);
    }
    __syncthreads();
#pragma unroll
    for (int k = 0; k < 8; k++) {
        int idx = base + k * 256 + t;
        if (idx < e) {
            int cF = d[k] >> BSHIFT;
            int slotF = cntF[cF] + rf[k];
            if (slotF < CAP) bktF[(size_t)cF * CAP + slotF] = (s[k] << 9) | (d[k] & BMASK);
            int cB = s[k] >> BSHIFT;
            int slotB = cntB[cB] + rb[k];
            if (slotB < CAP) bktB[(size_t)cB * CAP + slotB] = (d[k] << 9) | (s[k] & BMASK);
        }
    }
}

// ------- scan bucket sizes -> bucket bases (nb <= 256) ----------------------
__global__ __launch_bounds__(256) void bucket_scan(
    const int* __restrict__ gcurF, const int* __restrict__ gcurB,
    int* __restrict__ gbaseF, int* __restrict__ gbaseB,
    int* __restrict__ off_f, int* __restrict__ off_b,
    int nb, int n, int e) {
    const int* gcur = blockIdx.x ? gcurB : gcurF;
    int* gbase = blockIdx.x ? gbaseB : gbaseF;
    int* off = blockIdx.x ? off_b : off_f;
    __shared__ int sc[2][256];
    int t = threadIdx.x;
    int v = (t < nb) ? min(gcur[(size_t)t * PADI], CAP) : 0;
    sc[0][t] = v;
    __syncthreads();
    int pp = 0;
    for (int ofs = 1; ofs < 256; ofs <<= 1) {
        int u = sc[pp][t];
        if (t >= ofs) u += sc[pp][t - ofs];
        sc[pp ^ 1][t] = u;
        __syncthreads();
        pp ^= 1;
    }
    if (t < nb) gbase[t] = sc[pp][t] - v;    // exclusive
    if (t == 0) { gbase[nb] = e; off[n] = e; }
}

// ------- phase B: per-bucket CSR finalize (one block per bucket) ------------
__global__ __launch_bounds__(256) void bucket_csr(
    const int* __restrict__ bkt, const int* __restrict__ gcur,
    const int* __restrict__ gbase,
    int* __restrict__ csr, int* __restrict__ off, float* __restrict__ inv,
    int n, int nb) {
    __shared__ int cnt[BNODES];
    __shared__ int cur[BNODES];
    __shared__ int sc[2][BNODES];
    int c = blockIdx.x;
    int t = threadIdx.x;
    int size = gcur[(size_t)c * PADI];
    if (size > CAP) size = CAP;
    const int* src = bkt + (size_t)c * CAP;
    for (int l = t; l < BNODES; l += 256) cnt[l] = 0;
    __syncthreads();
    for (int i = t; i < size; i += 256)
        atomicAdd(&cnt[src[i] & BMASK], 1);
    __syncthreads();
    for (int l = t; l < BNODES; l += 256) sc[0][l] = cnt[l];
    __syncthreads();
    int pp = 0;
    for (int ofs = 1; ofs < BNODES; ofs <<= 1) {
        for (int l = t; l < BNODES; l += 256) {
            int u = sc[pp][l];
            if (l >= ofs) u += sc[pp][l - ofs];
            sc[pp ^ 1][l] = u;
        }
        __syncthreads();
        pp ^= 1;
    }
    int gb = gbase[c];
    for (int l = t; l < BNODES; l += 256) {
        int excl = sc[pp][l] - cnt[l];
        cur[l] = excl;
        int node = c * BNODES + l;
        if (node < n) {
            off[node] = gb + excl;
            inv[node] = 1.f / fmaxf((float)cnt[l], 1.f);
        }
    }
    __syncthreads();
    for (int i = t; i < size; i += 256) {
        int vk = src[i];
        int slot = atomicAdd(&cur[vk & BMASK], 1);
        csr[gb + slot] = vk >> 9;
    }
}

// ---- gather-mean over ONE 16-dim plane (both directions) -------------------
// 8 threads/node: 2 dirs x 4 lanes x ushort4. Plane = 3.2 MB -> per-XCD L2.
// csr: VECTORIZED nt loads (i32x4); agg: nt stores. Only the plane is cached.
__global__ __launch_bounds__(256) void gather_mean_pl(
    const ushort* __restrict__ Xp,
    const int* __restrict__ off_f, const int* __restrict__ csr_f,
    const float* __restrict__ invf,
    const int* __restrict__ off_b, const int* __restrict__ csr_b,
    const float* __restrict__ invb,
    ushort* __restrict__ aggfp, ushort* __restrict__ aggbp, int n) {
    int tid = blockIdx.x * 256 + threadIdx.x;
    int node = tid >> 3;
    if (node >= n) return;
    int sub = tid & 7;
    int dir = sub >> 2;
    int c = (sub & 3) * 4;
    const int* off = dir ? off_b : off_f;
    const int* csr = dir ? csr_b : csr_f;
    const float* inv = dir ? invb : invf;
    ushort* agg = dir ? aggbp : aggfp;

    int b = off[node], en = off[node + 1];
    float ax = 0.f, ay = 0.f, az = 0.f, aw = 0.f;
    int k = b;
    for (; k + 3 < en; k += 4) {
        i32x4 nb4 = __builtin_nontemporal_load(reinterpret_cast<const i32x4*>(csr + k));
        ushort4 v0 = *reinterpret_cast<const ushort4*>(Xp + (size_t)nb4.x * PD + c);
        ushort4 v1 = *reinterpret_cast<const ushort4*>(Xp + (size_t)nb4.y * PD + c);
        ushort4 v2 = *reinterpret_cast<const ushort4*>(Xp + (size_t)nb4.z * PD + c);
        ushort4 v3 = *reinterpret_cast<const ushort4*>(Xp + (size_t)nb4.w * PD + c);
        ax += bf2f(v0.x) + bf2f(v1.x) + bf2f(v2.x) + bf2f(v3.x);
        ay += bf2f(v0.y) + bf2f(v1.y) + bf2f(v2.y) + bf2f(v3.y);
        az += bf2f(v0.z) + bf2f(v1.z) + bf2f(v2.z) + bf2f(v3.z);
        aw += bf2f(v0.w) + bf2f(v1.w) + bf2f(v2.w) + bf2f(v3.w);
    }
    for (; k < en; k++) {
        int s = csr[k];
        ushort4 v = *reinterpret_cast<const ushort4*>(Xp + (size_t)s * PD + c);
        ax += bf2f(v.x); ay += bf2f(v.y); az += bf2f(v.z); aw += bf2f(v.w);
    }
    float iv = inv[node];
    us4 r;
    r.x = f2bf(ax * iv); r.y = f2bf(ay * iv); r.z = f2bf(az * iv); r.w = f2bf(aw * iv);
    __builtin_nontemporal_store(r, reinterpret_cast<us4*>(agg + (size_t)node * PD + c));
}

// ---------------- fused bidirectional SAGE layer (MFMA bf16, plane I/O) -----
// out_bf = relu(0.5*(aggf@Wlf^T + aggb@Wlb^T + xb@(Wrf+Wrb)^T) + 0.5*(blf+blb))
__global__ __launch_bounds__(256) void fused_sage_mfma(
    const ushort* __restrict__ Xb,
    const ushort* __restrict__ aggf, const ushort* __restrict__ aggb,
    const float* __restrict__ Wlf, const float* __restrict__ blf,
    const float* __restrict__ Wrf,
    const float* __restrict__ Wlb, const float* __restrict__ blb,
    const float* __restrict__ Wrb,
    ushort* __restrict__ OutB, int n)
{
    __shared__ ushort sA[64][72];       // +8 bf16 pad
    __shared__ ushort sW[3][64][72];    // bf16 weights, W[j][k] layout
    __shared__ float  sBias[64];
    const int t = threadIdx.x;
    const int base = blockIdx.x * 64;
    const int lane = t & 63;
    const int m0 = (t >> 6) * 16;       // wave's row offset
    const int lr = lane & 15;
    const int kb = lane >> 4;

    // ---- stage weights (bf16) + bias, once ----
#pragma unroll
    for (int i = 0; i < 4; i++) {
        int idx4 = t + 256 * i;               // 1024 float4s = 64x64
        int row = idx4 >> 4, c4 = idx4 & 15;
        float4 w0 = *reinterpret_cast<const float4*>(Wlf + row * 64 + c4 * 4);
        float4 w1 = *reinterpret_cast<const float4*>(Wlb + row * 64 + c4 * 4);
        float4 wa = *reinterpret_cast<const float4*>(Wrf + row * 64 + c4 * 4);
        float4 wb = *reinterpret_cast<const float4*>(Wrb + row * 64 + c4 * 4);
        ushort4 o;
        o.x = f2bf(w0.x); o.y = f2bf(w0.y); o.z = f2bf(w0.z); o.w = f2bf(w0.w);
        *reinterpret_cast<ushort4*>(&sW[0][row][c4 * 4]) = o;
        o.x = f2bf(w1.x); o.y = f2bf(w1.y); o.z = f2bf(w1.z); o.w = f2bf(w1.w);
        *reinterpret_cast<ushort4*>(&sW[1][row][c4 * 4]) = o;
        o.x = f2bf(wa.x + wb.x); o.y = f2bf(wa.y + wb.y);
        o.z = f2bf(wa.z + wb.z); o.w = f2bf(wa.w + wb.w);
        *reinterpret_cast<ushort4*>(&sW[2][row][c4 * 4]) = o;
    }
    if (t < 64) sBias[t] = 0.5f * (blf[t] + blb[t]);

    f32x4 acc0 = {0.f, 0.f, 0.f, 0.f};
    f32x4 acc1 = {0.f, 0.f, 0.f, 0.f};
    f32x4 acc2 = {0.f, 0.f, 0.f, 0.f};
    f32x4 acc3 = {0.f, 0.f, 0.f, 0.f};

    for (int p = 0; p < 3; p++) {
        const ushort* src = (p == 0) ? aggf : (p == 1) ? aggb : Xb;  // plane-major
        __syncthreads();
        // ---- stage A tile from 4 planes: 512 x 16B chunks ----
#pragma unroll
        for (int i = 0; i < 2; i++) {
            int c8 = t + 256 * i;             // 0..511
            int row = c8 >> 3;
            int q = (c8 >> 1) & 3;
            int h = (c8 & 1) * 8;
            int node = base + row;
            uint4 v = make_uint4(0u, 0u, 0u, 0u);
            if (node < n)
                v = *reinterpret_cast<const uint4*>(src + ((size_t)q * n + node) * PD + h);
            *reinterpret_cast<uint4*>(&sA[row][q * 16 + h]) = v;
        }
        __syncthreads();
        // ---- MFMA: 2 k-halves x 4 col-blocks ----
#pragma unroll
        for (int kh = 0; kh < 2; kh++) {
            bf16x8 a = *(const bf16x8*)(&sA[m0 + lr][kh * 32 + kb * 8]);
            bf16x8 b0 = *(const bf16x8*)(&sW[p][0 * 16 + lr][kh * 32 + kb * 8]);
            bf16x8 b1 = *(const bf16x8*)(&sW[p][1 * 16 + lr][kh * 32 + kb * 8]);
            bf16x8 b2 = *(const bf16x8*)(&sW[p][2 * 16 + lr][kh * 32 + kb * 8]);
            bf16x8 b3 = *(const bf16x8*)(&sW[p][3 * 16 + lr][kh * 32 + kb * 8]);
            acc0 = __builtin_amdgcn_mfma_f32_16x16x32_bf16(a, b0, acc0, 0, 0, 0);
            acc1 = __builtin_amdgcn_mfma_f32_16x16x32_bf16(a, b1, acc1, 0, 0, 0);
            acc2 = __builtin_amdgcn_mfma_f32_16x16x32_bf16(a, b2, acc2, 0, 0, 0);
            acc3 = __builtin_amdgcn_mfma_f32_16x16x32_bf16(a, b3, acc3, 0, 0, 0);
        }
    }
    // ---- epilogue: bias + relu + bf16 plane store ----
#pragma unroll
    for (int b = 0; b < 4; b++) {
        int j = lr + 16 * b;
        float bias = sBias[j];
        f32x4 ac = (b == 0) ? acc0 : (b == 1) ? acc1 : (b == 2) ? acc2 : acc3;
#pragma unroll
        for (int i = 0; i < 4; i++) {
            int row = base + m0 + kb * 4 + i;
            if (row < n) {
                float v = 0.5f * ac[i] + bias;
                v = v > 0.f ? v : 0.f;
                OutB[((size_t)(j >> 4) * n + row) * PD + (j & 15)] = f2bf(v);
            }
        }
    }
}

// ---- pooling: plane-coalesced, register accumulate, flush on graph change --
__global__ __launch_bounds__(256) void pool_partial(const ushort* __restrict__ H,
                                                    const int* __restrict__ batch,
                                                    float* __restrict__ psum,
                                                    float* __restrict__ pcnt, int n) {
    __shared__ float ls[GG * 64];
    __shared__ float lc[GG];
    int t = threadIdx.x;
    for (int i = t; i < GG * 64; i += 256) ls[i] = 0.f;
    for (int i = t; i < GG; i += 256) lc[i] = 0.f;
    __syncthreads();
    int chunk = (n + gridDim.x - 1) / gridDim.x;
    int base = blockIdx.x * chunk;
    int end = base + chunk; if (end > n) end = n;
    int nr = t >> 2;          // node offset 0..63
    int c  = (t & 3) * 4;     // dim chunk within plane

    float4 acc[4];
#pragma unroll
    for (int q = 0; q < 4; q++) acc[q] = make_float4(0.f, 0.f, 0.f, 0.f);
    int cnt = 0; int curg = -1;

#define POOL_FLUSH() do { if (curg >= 0) {                                   \
        _Pragma("unroll")                                                    \
        for (int q = 0; q < 4; q++) {                                        \
            atomicAdd(&ls[curg * 64 + q * 16 + c + 0], acc[q].x);            \
            atomicAdd(&ls[curg * 64 + q * 16 + c + 1], acc[q].y);            \
            atomicAdd(&ls[curg * 64 + q * 16 + c + 2], acc[q].z);            \
            atomicAdd(&ls[curg * 64 + q * 16 + c + 3], acc[q].w);            \
        }                                                                    \
        if ((t & 3) == 0) atomicAdd(&lc[curg], (float)cnt); } } while (0)

    for (int node = base + nr; node < end; node += 64) {
        int g = batch[node];
        if (g != curg) {
            POOL_FLUSH();
            curg = g; cnt = 0;
#pragma unroll
            for (int q = 0; q < 4; q++) acc[q] = make_float4(0.f, 0.f, 0.f, 0.f);
        }
#pragma unroll
        for (int q = 0; q < 4; q++) {
            ushort4 v = *reinterpret_cast<const ushort4*>(H + ((size_t)q * n + node) * PD + c);
            acc[q].x += bf2f(v.x); acc[q].y += bf2f(v.y);
            acc[q].z += bf2f(v.z); acc[q].w += bf2f(v.w);
        }
        cnt++;
    }
    POOL_FLUSH();
#undef POOL_FLUSH
    __syncthreads();
    for (int i = t; i < GG * 64; i += 256) {
        float v = ls[i];
        if (v != 0.f) atomicAdd(&psum[i], v);
    }
    for (int i = t; i < GG; i += 256) {
        float v = lc[i];
        if (v != 0.f) atomicAdd(&pcnt[i], v);
    }
}

// ---------------- head ----------------
__global__ __launch_bounds__(256) void pool_final(const float* __restrict__ psum,
                                                  const float* __restrict__ pcnt,
                                                  const float* __restrict__ PW,
                                                  const float* __restrict__ Pb,
                                                  float* __restrict__ out) {
    int t = blockIdx.x * 256 + threadIdx.x;
    int g = t >> 4, o = t & 15;
    if (g >= GG) return;
    float inv = 1.f / fmaxf(pcnt[g], 1.f);
    float acc = 0.f;
#pragma unroll 8
    for (int k = 0; k < 64; k++) acc += psum[g * 64 + k] * PW[o * 64 + k];
    out[t] = acc * inv + Pb[o];
}

extern "C" void kernel_launch(void* const* d_in, const int* in_sizes, int n_in,
                              void* d_out, int out_size, void* d_ws, size_t ws_size,
                              hipStream_t stream) {
    const float* x      = (const float*)d_in[0];
    const int*   ei     = (const int*)d_in[1];
    const int*   batch  = (const int*)d_in[2];
    const float* l0f_Wl = (const float*)d_in[4];
    const float* l0f_bl = (const float*)d_in[5];
    const float* l0f_Wr = (const float*)d_in[6];
    const float* l0b_Wl = (const float*)d_in[7];
    const float* l0b_bl = (const float*)d_in[8];
    const float* l0b_Wr = (const float*)d_in[9];
    const float* l1f_Wl = (const float*)d_in[10];
    const float* l1f_bl = (const float*)d_in[11];
    const float* l1f_Wr = (const float*)d_in[12];
    const float* l1b_Wl = (const float*)d_in[13];
    const float* l1b_bl = (const float*)d_in[14];
    const float* l1b_Wr = (const float*)d_in[15];
    const float* pred_W = (const float*)d_in[16];
    const float* pred_b = (const float*)d_in[17];

    const int n = in_sizes[0] / 64;
    const int e = in_sizes[1] / 2;
    const int nb = (n + BNODES - 1) >> BSHIFT;   // <= 256 required
    const size_t npl = (size_t)n * PD;           // elements per plane

    // ---- workspace layout (int elements) ----
    int* ws = (int*)d_ws;
    size_t o = 0;
    int*   gcurF = ws + o;  o += (size_t)nb * PADI;      // zeroed
    int*   gcurB = ws + o;  o += (size_t)nb * PADI;      // zeroed
    float* psum  = (float*)(ws + o); o += GG * 64;       // zeroed
    float* pcnt  = (float*)(ws + o); o += GG;            // zeroed
    size_t zcount = o;
    int*   gbaseF = ws + o; o += nb + 1;
    int*   gbaseB = ws + o; o += nb + 1;
    int*   off_f = ws + o;  o += n + 1;
    int*   off_b = ws + o;  o += n + 1;
    float* invf  = (float*)(ws + o); o += n;
    float* invb  = (float*)(ws + o); o += n;
    int*   csr_f = ws + o;  o += e;
    int*   csr_b = ws + o;  o += e;
    o = (o + 3) & ~(size_t)3;
    int*   bktF  = ws + o;  o += (size_t)nb * CAP;       // packed entries
    int*   bktB  = ws + o;  o += (size_t)nb * CAP;
    ushort* xb    = (ushort*)(ws + o); o += (size_t)n * 32;  // 4 planes (x->h0->h1)
    ushort* aggfb = (ushort*)(ws + o); o += (size_t)n * 32;  // 4 planes
    ushort* aggbb = (ushort*)(ws + o); o += (size_t)n * 32;  // 4 planes

    hipMemsetAsync(ws, 0, zcount * sizeof(int), stream);

    // ---- CSR build via bucket counting-sort ----
    to_bf16_pl<<<((size_t)n * 16 + 255) / 256, 256, 0, stream>>>(x, xb, n);
    bucket_scatter<<<(e + 2047) / 2048, 256, 2 * nb * sizeof(int), stream>>>(
        ei, gcurF, gcurB, bktF, bktB, e, nb);
    bucket_scan<<<2, 256, 0, stream>>>(gcurF, gcurB, gbaseF, gbaseB,
                                       off_f, off_b, nb, n, e);
    bucket_csr<<<nb, 256, 0, stream>>>(bktF, gcurF, gbaseF, csr_f, off_f, invf, n, nb);
    bucket_csr<<<nb, 256, 0, stream>>>(bktB, gcurB, gbaseB, csr_b, off_b, invb, n, nb);

    const int ggrid = ((size_t)n * 8 + 255) / 256;

    // layer 0: per-plane gather (L2-resident plane, nt streams), MFMA sage
    for (int q = 0; q < NPL; q++)
        gather_mean_pl<<<ggrid, 256, 0, stream>>>(
            xb + q * npl, off_f, csr_f, invf, off_b, csr_b, invb,
            aggfb + q * npl, aggbb + q * npl, n);
    fused_sage_mfma<<<(n + 63) / 64, 256, 0, stream>>>(xb, aggfb, aggbb,
        l0f_Wl, l0f_bl, l0f_Wr, l0b_Wl, l0b_bl, l0b_Wr, xb, n);

    // layer 1
    for (int q = 0; q < NPL; q++)
        gather_mean_pl<<<ggrid, 256, 0, stream>>>(
            xb + q * npl, off_f, csr_f, invf, off_b, csr_b, invb,
            aggfb + q * npl, aggbb + q * npl, n);
    fused_sage_mfma<<<(n + 63) / 64, 256, 0, stream>>>(xb, aggfb, aggbb,
        l1f_Wl, l1f_bl, l1f_Wr, l1b_Wl, l1b_bl, l1b_Wr, xb, n);

    // pooling + head
    pool_partial<<<256, 256, 0, stream>>>(xb, batch, psum, pcnt, n);
    pool_final<<<8, 256, 0, stream>>>(psum, pcnt, pred_W, pred_b, (float*)d_out);
}

// Round 14
// 274.084 us; speedup vs baseline: 1.3524x; 1.3355x over previous
//
#include <hip/hip_runtime.h>
#include <hip/hip_bf16.h>

#define GG 128      // num_graphs (static in problem)
#define BSHIFT 9    // 512 nodes per bucket
#define BMASK 511
#define BNODES 512
#define PADI 16     // ints per padded global bucket counter (one 64B line each)
#define CAP 8192    // bucket capacity (mean ~5100 at n=100k,e=1M)

typedef __attribute__((ext_vector_type(8))) short bf16x8;
typedef __attribute__((ext_vector_type(4))) float f32x4;

// ---------------- bf16 helpers (RNE) ----------------
__device__ __forceinline__ ushort f2bf(float f) {
    union { float f; unsigned u; } v; v.f = f;
    unsigned r = v.u + 0x7FFF + ((v.u >> 16) & 1);
    return (ushort)(r >> 16);
}
__device__ __forceinline__ float bf2f(ushort s) {
    union { unsigned u; float f; } v; v.u = ((unsigned)s) << 16;
    return v.f;
}

// ---------------- workspace zeroing (replaces slow in-graph memset) ---------
__global__ __launch_bounds__(256) void zero_ws(int* __restrict__ p, int count) {
    int i = blockIdx.x * 256 + threadIdx.x;
    if (i < count) p[i] = 0;
}

// ---------------- f32 -> bf16 convert (vectorized, row-major) ---------------
__global__ __launch_bounds__(256) void to_bf16(const float* __restrict__ X,
                                               ushort* __restrict__ Xb, int n4) {
    int i = blockIdx.x * 256 + threadIdx.x;
    if (i >= n4) return;
    float4 v = reinterpret_cast<const float4*>(X)[i];
    ushort4 o;
    o.x = f2bf(v.x); o.y = f2bf(v.y); o.z = f2bf(v.z); o.w = f2bf(v.w);
    reinterpret_cast<ushort4*>(Xb)[i] = o;
}

// ------- phase A: bucket edges by coarse key, PACKED entries ----------------
// entry = (neighbor_value << 9) | (key & 511); value < 2^17 (n <= 131072)
__global__ __launch_bounds__(256) void bucket_scatter(
    const int* __restrict__ ei,
    int* __restrict__ gcurF, int* __restrict__ gcurB,
    int* __restrict__ bktF, int* __restrict__ bktB,
    int e, int nb) {
    extern __shared__ int lds[];             // cntF[nb], cntB[nb]
    int* cntF = lds;
    int* cntB = lds + nb;
    int t = threadIdx.x;
    for (int i = t; i < 2 * nb; i += 256) lds[i] = 0;
    __syncthreads();
    int base = blockIdx.x * 2048;
    int s[8], d[8], rf[8], rb[8];
#pragma unroll
    for (int k = 0; k < 8; k++) {
        int idx = base + k * 256 + t;
        if (idx < e) {
            s[k] = ei[idx];
            d[k] = ei[e + idx];
            rf[k] = atomicAdd(&cntF[d[k] >> BSHIFT], 1);
            rb[k] = atomicAdd(&cntB[s[k] >> BSHIFT], 1);
        }
    }
    __syncthreads();
    for (int c = t; c < nb; c += 256) {
        int vF = cntF[c];
        if (vF) cntF[c] = atomicAdd(&gcurF[(size_t)c * PADI], vF);
        int vB = cntB[c];
        if (vB) cntB[c] = atomicAdd(&gcurB[(size_t)c * PADI], vB);
    }
    __syncthreads();
#pragma unroll
    for (int k = 0; k < 8; k++) {
        int idx = base + k * 256 + t;
        if (idx < e) {
            int cF = d[k] >> BSHIFT;
            int slotF = cntF[cF] + rf[k];
            if (slotF < CAP) bktF[(size_t)cF * CAP + slotF] = (s[k] << 9) | (d[k] & BMASK);
            int cB = s[k] >> BSHIFT;
            int slotB = cntB[cB] + rb[k];
            if (slotB < CAP) bktB[(size_t)cB * CAP + slotB] = (d[k] << 9) | (s[k] & BMASK);
        }
    }
}

// ------- scan bucket sizes -> bucket bases (nb <= 256) ----------------------
__global__ __launch_bounds__(256) void bucket_scan(
    const int* __restrict__ gcurF, const int* __restrict__ gcurB,
    int* __restrict__ gbaseF, int* __restrict__ gbaseB,
    int* __restrict__ off_f, int* __restrict__ off_b,
    int nb, int n, int e) {
    const int* gcur = blockIdx.x ? gcurB : gcurF;
    int* gbase = blockIdx.x ? gbaseB : gbaseF;
    int* off = blockIdx.x ? off_b : off_f;
    __shared__ int sc[2][256];
    int t = threadIdx.x;
    int v = (t < nb) ? min(gcur[(size_t)t * PADI], CAP) : 0;
    sc[0][t] = v;
    __syncthreads();
    int pp = 0;
    for (int ofs = 1; ofs < 256; ofs <<= 1) {
        int u = sc[pp][t];
        if (t >= ofs) u += sc[pp][t - ofs];
        sc[pp ^ 1][t] = u;
        __syncthreads();
        pp ^= 1;
    }
    if (t < nb) gbase[t] = sc[pp][t] - v;    // exclusive
    if (t == 0) { gbase[nb] = e; off[n] = e; }
}

// ------- phase B: per-bucket CSR finalize (one block per bucket) ------------
__global__ __launch_bounds__(256) void bucket_csr(
    const int* __restrict__ bkt, const int* __restrict__ gcur,
    const int* __restrict__ gbase,
    int* __restrict__ csr, int* __restrict__ off, float* __restrict__ inv,
    int n, int nb) {
    __shared__ int cnt[BNODES];
    __shared__ int cur[BNODES];
    __shared__ int sc[2][BNODES];
    int c = blockIdx.x;
    int t = threadIdx.x;
    int size = gcur[(size_t)c * PADI];
    if (size > CAP) size = CAP;
    const int* src = bkt + (size_t)c * CAP;
    for (int l = t; l < BNODES; l += 256) cnt[l] = 0;
    __syncthreads();
    for (int i = t; i < size; i += 256)
        atomicAdd(&cnt[src[i] & BMASK], 1);
    __syncthreads();
    for (int l = t; l < BNODES; l += 256) sc[0][l] = cnt[l];
    __syncthreads();
    int pp = 0;
    for (int ofs = 1; ofs < BNODES; ofs <<= 1) {
        for (int l = t; l < BNODES; l += 256) {
            int u = sc[pp][l];
            if (l >= ofs) u += sc[pp][l - ofs];
            sc[pp ^ 1][l] = u;
        }
        __syncthreads();
        pp ^= 1;
    }
    int gb = gbase[c];
    for (int l = t; l < BNODES; l += 256) {
        int excl = sc[pp][l] - cnt[l];
        cur[l] = excl;
        int node = c * BNODES + l;
        if (node < n) {
            off[node] = gb + excl;
            inv[node] = 1.f / fmaxf((float)cnt[l], 1.f);
        }
    }
    __syncthreads();
    for (int i = t; i < size; i += 256) {
        int vk = src[i];
        int slot = atomicAdd(&cur[vk & BMASK], 1);
        csr[gb + slot] = vk >> 9;
    }
}

// ---- gather-mean: bf16 row-major reads, f32 accumulate, bf16 agg writes ----
__global__ __launch_bounds__(256) void gather_mean_bf(
    const ushort* __restrict__ Xb,
    const int* __restrict__ off_f, const int* __restrict__ csr_f,
    const float* __restrict__ invf,
    const int* __restrict__ off_b, const int* __restrict__ csr_b,
    const float* __restrict__ invb,
    ushort* __restrict__ aggf, ushort* __restrict__ aggb, int n) {
    int tid = blockIdx.x * 256 + threadIdx.x;
    int node = tid >> 5;
    if (node >= n) return;
    int dir = (tid >> 4) & 1;
    int c = (tid & 15) * 4;
    const int* off = dir ? off_b : off_f;
    const int* csr = dir ? csr_b : csr_f;
    const float* inv = dir ? invb : invf;
    ushort* agg = dir ? aggb : aggf;

    int b = off[node], en = off[node + 1];
    float ax = 0.f, ay = 0.f, az = 0.f, aw = 0.f;
    int k = b;
    for (; k + 3 < en; k += 4) {
        int n0 = csr[k], n1 = csr[k + 1], n2 = csr[k + 2], n3 = csr[k + 3];
        ushort4 v0 = *reinterpret_cast<const ushort4*>(Xb + (size_t)n0 * 64 + c);
        ushort4 v1 = *reinterpret_cast<const ushort4*>(Xb + (size_t)n1 * 64 + c);
        ushort4 v2 = *reinterpret_cast<const ushort4*>(Xb + (size_t)n2 * 64 + c);
        ushort4 v3 = *reinterpret_cast<const ushort4*>(Xb + (size_t)n3 * 64 + c);
        ax += bf2f(v0.x) + bf2f(v1.x) + bf2f(v2.x) + bf2f(v3.x);
        ay += bf2f(v0.y) + bf2f(v1.y) + bf2f(v2.y) + bf2f(v3.y);
        az += bf2f(v0.z) + bf2f(v1.z) + bf2f(v2.z) + bf2f(v3.z);
        aw += bf2f(v0.w) + bf2f(v1.w) + bf2f(v2.w) + bf2f(v3.w);
    }
    for (; k < en; k++) {
        int s = csr[k];
        ushort4 v = *reinterpret_cast<const ushort4*>(Xb + (size_t)s * 64 + c);
        ax += bf2f(v.x); ay += bf2f(v.y); az += bf2f(v.z); aw += bf2f(v.w);
    }
    float iv = inv[node];
    ushort4 r;
    r.x = f2bf(ax * iv); r.y = f2bf(ay * iv); r.z = f2bf(az * iv); r.w = f2bf(aw * iv);
    *reinterpret_cast<ushort4*>(agg + (size_t)node * 64 + c) = r;
}

// ---------------- fused bidirectional SAGE layer (MFMA bf16, row-major) -----
// out_bf = relu(0.5*(aggf@Wlf^T + aggb@Wlb^T + xb@(Wrf+Wrb)^T) + 0.5*(blf+blb))
// Fragment layouts (m89-verified family):
//   A[m][k]: m=lane&15, k=(lane>>4)*8+j   B[k][j]: k=(lane>>4)*8+j, j=lane&15
//   D[m][j]: m=(lane>>4)*4+reg, j=lane&15
__global__ __launch_bounds__(256) void fused_sage_mfma(
    const ushort* __restrict__ Xb,
    const ushort* __restrict__ aggf, const ushort* __restrict__ aggb,
    const float* __restrict__ Wlf, const float* __restrict__ blf,
    const float* __restrict__ Wrf,
    const float* __restrict__ Wlb, const float* __restrict__ blb,
    const float* __restrict__ Wrb,
    ushort* __restrict__ OutB, int n)
{
    __shared__ ushort sA[64][72];       // +8 bf16 pad: 144B stride -> 4-bank step
    __shared__ ushort sW[3][64][72];    // bf16 weights, W[j][k] layout
    __shared__ float  sBias[64];
    const int t = threadIdx.x;
    const int base = blockIdx.x * 64;
    const int lane = t & 63;
    const int m0 = (t >> 6) * 16;       // wave's row offset
    const int lr = lane & 15;           // A row / B col / D col
    const int kb = lane >> 4;           // k-block 0..3

    // ---- stage weights (bf16) + bias, once ----
#pragma unroll
    for (int i = 0; i < 4; i++) {
        int idx4 = t + 256 * i;               // 1024 float4s = 64x64
        int row = idx4 >> 4, c4 = idx4 & 15;
        float4 w0 = *reinterpret_cast<const float4*>(Wlf + row * 64 + c4 * 4);
        float4 w1 = *reinterpret_cast<const float4*>(Wlb + row * 64 + c4 * 4);
        float4 wa = *reinterpret_cast<const float4*>(Wrf + row * 64 + c4 * 4);
        float4 wb = *reinterpret_cast<const float4*>(Wrb + row * 64 + c4 * 4);
        ushort4 o;
        o.x = f2bf(w0.x); o.y = f2bf(w0.y); o.z = f2bf(w0.z); o.w = f2bf(w0.w);
        *reinterpret_cast<ushort4*>(&sW[0][row][c4 * 4]) = o;
        o.x = f2bf(w1.x); o.y = f2bf(w1.y); o.z = f2bf(w1.z); o.w = f2bf(w1.w);
        *reinterpret_cast<ushort4*>(&sW[1][row][c4 * 4]) = o;
        o.x = f2bf(wa.x + wb.x); o.y = f2bf(wa.y + wb.y);
        o.z = f2bf(wa.z + wb.z); o.w = f2bf(wa.w + wb.w);
        *reinterpret_cast<ushort4*>(&sW[2][row][c4 * 4]) = o;
    }
    if (t < 64) sBias[t] = 0.5f * (blf[t] + blb[t]);

    f32x4 acc0 = {0.f, 0.f, 0.f, 0.f};
    f32x4 acc1 = {0.f, 0.f, 0.f, 0.f};
    f32x4 acc2 = {0.f, 0.f, 0.f, 0.f};
    f32x4 acc3 = {0.f, 0.f, 0.f, 0.f};

    for (int p = 0; p < 3; p++) {
        const ushort* src = (p == 0) ? aggf : (p == 1) ? aggb : Xb;
        __syncthreads();   // protect sA from previous pass readers (and sW stage)
        // ---- stage A tile: 64 rows x 64 bf16, 16B per thread x2 ----
#pragma unroll
        for (int i = 0; i < 2; i++) {
            int c8 = t + 256 * i;             // 512 chunks of 8 bf16
            int row = c8 >> 3, k8 = (c8 & 7) * 8;
            int node = base + row;
            uint4 v = make_uint4(0u, 0u, 0u, 0u);
            if (node < n)
                v = *reinterpret_cast<const uint4*>(src + (size_t)node * 64 + k8);
            *reinterpret_cast<uint4*>(&sA[row][k8]) = v;
        }
        __syncthreads();
        // ---- MFMA: 2 k-halves x 4 col-blocks ----
#pragma unroll
        for (int kh = 0; kh < 2; kh++) {
            bf16x8 a = *(const bf16x8*)(&sA[m0 + lr][kh * 32 + kb * 8]);
            bf16x8 b0 = *(const bf16x8*)(&sW[p][0 * 16 + lr][kh * 32 + kb * 8]);
            bf16x8 b1 = *(const bf16x8*)(&sW[p][1 * 16 + lr][kh * 32 + kb * 8]);
            bf16x8 b2 = *(const bf16x8*)(&sW[p][2 * 16 + lr][kh * 32 + kb * 8]);
            bf16x8 b3 = *(const bf16x8*)(&sW[p][3 * 16 + lr][kh * 32 + kb * 8]);
            acc0 = __builtin_amdgcn_mfma_f32_16x16x32_bf16(a, b0, acc0, 0, 0, 0);
            acc1 = __builtin_amdgcn_mfma_f32_16x16x32_bf16(a, b1, acc1, 0, 0, 0);
            acc2 = __builtin_amdgcn_mfma_f32_16x16x32_bf16(a, b2, acc2, 0, 0, 0);
            acc3 = __builtin_amdgcn_mfma_f32_16x16x32_bf16(a, b3, acc3, 0, 0, 0);
        }
    }
    // ---- epilogue: bias + relu + bf16 store ----
    // D: row m = m0 + kb*4 + i, col j = lr + 16*b
#pragma unroll
    for (int b = 0; b < 4; b++) {
        int j = lr + 16 * b;
        float bias = sBias[j];
        f32x4 ac = (b == 0) ? acc0 : (b == 1) ? acc1 : (b == 2) ? acc2 : acc3;
#pragma unroll
        for (int i = 0; i < 4; i++) {
            int row = base + m0 + kb * 4 + i;
            if (row < n) {
                float v = 0.5f * ac[i] + bias;
                v = v > 0.f ? v : 0.f;
                OutB[(size_t)row * 64 + j] = f2bf(v);
            }
        }
    }
}

// ---- pooling: sorted batch -> register accumulate, flush on graph change ---
__global__ __launch_bounds__(256) void pool_partial(const ushort* __restrict__ H,
                                                    const int* __restrict__ batch,
                                                    float* __restrict__ psum,
                                                    float* __restrict__ pcnt, int n) {
    __shared__ float ls[GG * 64];
    __shared__ float lc[GG];
    int t = threadIdx.x;
    for (int i = t; i < GG * 64; i += 256) ls[i] = 0.f;
    for (int i = t; i < GG; i += 256) lc[i] = 0.f;
    __syncthreads();
    int chunk = (n + gridDim.x - 1) / gridDim.x;
    int base = blockIdx.x * chunk;
    int end = base + chunk; if (end > n) end = n;
    int f = t & 63, r = t >> 6;
    float acc = 0.f; int cnt = 0; int curg = -1;
    for (int node = base + r; node < end; node += 4) {
        int g = batch[node];
        if (g != curg) {
            if (curg >= 0) {
                atomicAdd(&ls[curg * 64 + f], acc);
                if (f == 0) atomicAdd(&lc[curg], (float)cnt);
            }
            curg = g; acc = 0.f; cnt = 0;
        }
        acc += bf2f(H[(size_t)node * 64 + f]);
        cnt++;
    }
    if (curg >= 0) {
        atomicAdd(&ls[curg * 64 + f], acc);
        if (f == 0) atomicAdd(&lc[curg], (float)cnt);
    }
    __syncthreads();
    for (int i = t; i < GG * 64; i += 256) {
        float v = ls[i];
        if (v != 0.f) atomicAdd(&psum[i], v);
    }
    for (int i = t; i < GG; i += 256) {
        float v = lc[i];
        if (v != 0.f) atomicAdd(&pcnt[i], v);
    }
}

// ---------------- head ----------------
__global__ __launch_bounds__(256) void pool_final(const float* __restrict__ psum,
                                                  const float* __restrict__ pcnt,
                                                  const float* __restrict__ PW,
                                                  const float* __restrict__ Pb,
                                                  float* __restrict__ out) {
    int t = blockIdx.x * 256 + threadIdx.x;
    int g = t >> 4, o = t & 15;
    if (g >= GG) return;
    float inv = 1.f / fmaxf(pcnt[g], 1.f);
    float acc = 0.f;
#pragma unroll 8
    for (int k = 0; k < 64; k++) acc += psum[g * 64 + k] * PW[o * 64 + k];
    out[t] = acc * inv + Pb[o];
}

extern "C" void kernel_launch(void* const* d_in, const int* in_sizes, int n_in,
                              void* d_out, int out_size, void* d_ws, size_t ws_size,
                              hipStream_t stream) {
    const float* x      = (const float*)d_in[0];
    const int*   ei     = (const int*)d_in[1];
    const int*   batch  = (const int*)d_in[2];
    const float* l0f_Wl = (const float*)d_in[4];
    const float* l0f_bl = (const float*)d_in[5];
    const float* l0f_Wr = (const float*)d_in[6];
    const float* l0b_Wl = (const float*)d_in[7];
    const float* l0b_bl = (const float*)d_in[8];
    const float* l0b_Wr = (const float*)d_in[9];
    const float* l1f_Wl = (const float*)d_in[10];
    const float* l1f_bl = (const float*)d_in[11];
    const float* l1f_Wr = (const float*)d_in[12];
    const float* l1b_Wl = (const float*)d_in[13];
    const float* l1b_bl = (const float*)d_in[14];
    const float* l1b_Wr = (const float*)d_in[15];
    const float* pred_W = (const float*)d_in[16];
    const float* pred_b = (const float*)d_in[17];

    const int n = in_sizes[0] / 64;
    const int e = in_sizes[1] / 2;
    const int nb = (n + BNODES - 1) >> BSHIFT;   // <= 256 required

    // ---- workspace layout (int elements) ----
    int* ws = (int*)d_ws;
    size_t o = 0;
    int*   gcurF = ws + o;  o += (size_t)nb * PADI;      // zeroed
    int*   gcurB = ws + o;  o += (size_t)nb * PADI;      // zeroed
    float* psum  = (float*)(ws + o); o += GG * 64;       // zeroed
    float* pcnt  = (float*)(ws + o); o += GG;            // zeroed
    size_t zcount = o;
    int*   gbaseF = ws + o; o += nb + 1;
    int*   gbaseB = ws + o; o += nb + 1;
    int*   off_f = ws + o;  o += n + 1;
    int*   off_b = ws + o;  o += n + 1;
    float* invf  = (float*)(ws + o); o += n;
    float* invb  = (float*)(ws + o); o += n;
    int*   csr_f = ws + o;  o += e;
    int*   csr_b = ws + o;  o += e;
    o = (o + 3) & ~(size_t)3;
    int*   bktF  = ws + o;  o += (size_t)nb * CAP;       // packed entries
    int*   bktB  = ws + o;  o += (size_t)nb * CAP;
    ushort* xb    = (ushort*)(ws + o); o += (size_t)n * 32;  // [n][64] bf16 (x->h0->h1)
    ushort* aggfb = (ushort*)(ws + o); o += (size_t)n * 32;  // [n][64] bf16
    ushort* aggbb = (ushort*)(ws + o); o += (size_t)n * 32;  // [n][64] bf16

    // zero counters with our own kernel (hipMemsetAsync -> fillBufferAligned
    // measured 41 us for 57 KB in-graph; this is ~3 us)
    zero_ws<<<((int)zcount + 255) / 256, 256, 0, stream>>>(ws, (int)zcount);

    // ---- CSR build via bucket counting-sort ----
    to_bf16<<<((size_t)n * 16 + 255) / 256, 256, 0, stream>>>(x, xb, n * 16);
    bucket_scatter<<<(e + 2047) / 2048, 256, 2 * nb * sizeof(int), stream>>>(
        ei, gcurF, gcurB, bktF, bktB, e, nb);
    bucket_scan<<<2, 256, 0, stream>>>(gcurF, gcurB, gbaseF, gbaseB,
                                       off_f, off_b, nb, n, e);
    bucket_csr<<<nb, 256, 0, stream>>>(bktF, gcurF, gbaseF, csr_f, off_f, invf, n, nb);
    bucket_csr<<<nb, 256, 0, stream>>>(bktB, gcurB, gbaseB, csr_b, off_b, invb, n, nb);

    // layer 0: gather bf16(x) -> bf16 agg; MFMA sage -> h0 bf16 (in place)
    gather_mean_bf<<<((size_t)n * 32 + 255) / 256, 256, 0, stream>>>(
        xb, off_f, csr_f, invf, off_b, csr_b, invb, aggfb, aggbb, n);
    fused_sage_mfma<<<(n + 63) / 64, 256, 0, stream>>>(xb, aggfb, aggbb,
        l0f_Wl, l0f_bl, l0f_Wr, l0b_Wl, l0b_bl, l0b_Wr, xb, n);

    // layer 1: gather bf16(h0) -> bf16 agg; MFMA sage -> h1 bf16 (in place)
    gather_mean_bf<<<((size_t)n * 32 + 255) / 256, 256, 0, stream>>>(
        xb, off_f, csr_f, invf, off_b, csr_b, invb, aggfb, aggbb, n);
    fused_sage_mfma<<<(n + 63) / 64, 256, 0, stream>>>(xb, aggfb, aggbb,
        l1f_Wl, l1f_bl, l1f_Wr, l1b_Wl, l1b_bl, l1b_Wr, xb, n);

    // pooling + head
    pool_partial<<<256, 256, 0, stream>>>(xb, batch, psum, pcnt, n);
    pool_final<<<8, 256, 0, stream>>>(psum, pcnt, pred_W, pred_b, (float*)d_out);
}

// Round 15
// 234.193 us; speedup vs baseline: 1.5828x; 1.1703x over previous
//
#include <hip/hip_runtime.h>
#include <hip/hip_bf16.h>

#define GG 128      // num_graphs (static in problem)
#define BSHIFT 9    // 512 nodes per bucket
#define BMASK 511
#define BNODES 512
#define PADI 16     // ints per padded global bucket counter (one 64B line each)
#define CAP 8192    // bucket capacity (mean ~5100 at n=100k,e=1M)

typedef __attribute__((ext_vector_type(8))) short bf16x8;
typedef __attribute__((ext_vector_type(4))) float f32x4;
typedef __attribute__((ext_vector_type(2))) float f32x2;

// ---------------- bf16 helpers (RNE) ----------------
__device__ __forceinline__ ushort f2bf(float f) {
    union { float f; unsigned u; } v; v.f = f;
    unsigned r = v.u + 0x7FFF + ((v.u >> 16) & 1);
    return (ushort)(r >> 16);
}
__device__ __forceinline__ float bf2f(ushort s) {
    union { unsigned u; float f; } v; v.u = ((unsigned)s) << 16;
    return v.f;
}

// ---------------- fp8 helpers (native gfx950 converters) ----------------
__device__ __forceinline__ unsigned enc4fp8(float v0, float v1, float v2, float v3) {
    int p = __builtin_amdgcn_cvt_pk_fp8_f32(v0, v1, 0, false);
    p = __builtin_amdgcn_cvt_pk_fp8_f32(v2, v3, p, true);
    return (unsigned)p;
}
__device__ __forceinline__ unsigned char enc1fp8(float v) {
    return (unsigned char)(__builtin_amdgcn_cvt_pk_fp8_f32(v, v, 0, false) & 0xFF);
}

// ---------------- workspace zeroing ----------------
__global__ __launch_bounds__(256) void zero_ws(int* __restrict__ p, int count) {
    int i = blockIdx.x * 256 + threadIdx.x;
    if (i < count) p[i] = 0;
}

// ------- f32 -> bf16 row-major + fp8 row-major (both) -----------------------
__global__ __launch_bounds__(256) void to_bf16_fp8(const float* __restrict__ X,
                                                   ushort* __restrict__ Xb,
                                                   unsigned* __restrict__ Xq, int n4) {
    int i = blockIdx.x * 256 + threadIdx.x;
    if (i >= n4) return;
    float4 v = reinterpret_cast<const float4*>(X)[i];
    ushort4 o;
    o.x = f2bf(v.x); o.y = f2bf(v.y); o.z = f2bf(v.z); o.w = f2bf(v.w);
    reinterpret_cast<ushort4*>(Xb)[i] = o;
    Xq[i] = enc4fp8(v.x, v.y, v.z, v.w);
}

// ------- phase A: bucket edges by coarse key, PACKED entries ----------------
// entry = (neighbor_value << 9) | (key & 511); value < 2^17 (n <= 131072)
__global__ __launch_bounds__(256) void bucket_scatter(
    const int* __restrict__ ei,
    int* __restrict__ gcurF, int* __restrict__ gcurB,
    int* __restrict__ bktF, int* __restrict__ bktB,
    int e, int nb) {
    extern __shared__ int lds[];             // cntF[nb], cntB[nb]
    int* cntF = lds;
    int* cntB = lds + nb;
    int t = threadIdx.x;
    for (int i = t; i < 2 * nb; i += 256) lds[i] = 0;
    __syncthreads();
    int base = blockIdx.x * 2048;
    int s[8], d[8], rf[8], rb[8];
#pragma unroll
    for (int k = 0; k < 8; k++) {
        int idx = base + k * 256 + t;
        if (idx < e) {
            s[k] = ei[idx];
            d[k] = ei[e + idx];
            rf[k] = atomicAdd(&cntF[d[k] >> BSHIFT], 1);
            rb[k] = atomicAdd(&cntB[s[k] >> BSHIFT], 1);
        }
    }
    __syncthreads();
    for (int c = t; c < nb; c += 256) {
        int vF = cntF[c];
        if (vF) cntF[c] = atomicAdd(&gcurF[(size_t)c * PADI], vF);
        int vB = cntB[c];
        if (vB) cntB[c] = atomicAdd(&gcurB[(size_t)c * PADI], vB);
    }
    __syncthreads();
#pragma unroll
    for (int k = 0; k < 8; k++) {
        int idx = base + k * 256 + t;
        if (idx < e) {
            int cF = d[k] >> BSHIFT;
            int slotF = cntF[cF] + rf[k];
            if (slotF < CAP) bktF[(size_t)cF * CAP + slotF] = (s[k] << 9) | (d[k] & BMASK);
            int cB = s[k] >> BSHIFT;
            int slotB = cntB[cB] + rb[k];
            if (slotB < CAP) bktB[(size_t)cB * CAP + slotB] = (d[k] << 9) | (s[k] & BMASK);
        }
    }
}

// ------- scan bucket sizes -> bucket bases (nb <= 256) ----------------------
__global__ __launch_bounds__(256) void bucket_scan(
    const int* __restrict__ gcurF, const int* __restrict__ gcurB,
    int* __restrict__ gbaseF, int* __restrict__ gbaseB,
    int* __restrict__ off_f, int* __restrict__ off_b,
    int nb, int n, int e) {
    const int* gcur = blockIdx.x ? gcurB : gcurF;
    int* gbase = blockIdx.x ? gbaseB : gbaseF;
    int* off = blockIdx.x ? off_b : off_f;
    __shared__ int sc[2][256];
    int t = threadIdx.x;
    int v = (t < nb) ? min(gcur[(size_t)t * PADI], CAP) : 0;
    sc[0][t] = v;
    __syncthreads();
    int pp = 0;
    for (int ofs = 1; ofs < 256; ofs <<= 1) {
        int u = sc[pp][t];
        if (t >= ofs) u += sc[pp][t - ofs];
        sc[pp ^ 1][t] = u;
        __syncthreads();
        pp ^= 1;
    }
    if (t < nb) gbase[t] = sc[pp][t] - v;    // exclusive
    if (t == 0) { gbase[nb] = e; off[n] = e; }
}

// ------- phase B: per-bucket CSR finalize (one block per bucket) ------------
__global__ __launch_bounds__(256) void bucket_csr(
    const int* __restrict__ bkt, const int* __restrict__ gcur,
    const int* __restrict__ gbase,
    int* __restrict__ csr, int* __restrict__ off, float* __restrict__ inv,
    int n, int nb) {
    __shared__ int cnt[BNODES];
    __shared__ int cur[BNODES];
    __shared__ int sc[2][BNODES];
    int c = blockIdx.x;
    int t = threadIdx.x;
    int size = gcur[(size_t)c * PADI];
    if (size > CAP) size = CAP;
    const int* src = bkt + (size_t)c * CAP;
    for (int l = t; l < BNODES; l += 256) cnt[l] = 0;
    __syncthreads();
    for (int i = t; i < size; i += 256)
        atomicAdd(&cnt[src[i] & BMASK], 1);
    __syncthreads();
    for (int l = t; l < BNODES; l += 256) sc[0][l] = cnt[l];
    __syncthreads();
    int pp = 0;
    for (int ofs = 1; ofs < BNODES; ofs <<= 1) {
        for (int l = t; l < BNODES; l += 256) {
            int u = sc[pp][l];
            if (l >= ofs) u += sc[pp][l - ofs];
            sc[pp ^ 1][l] = u;
        }
        __syncthreads();
        pp ^= 1;
    }
    int gb = gbase[c];
    for (int l = t; l < BNODES; l += 256) {
        int excl = sc[pp][l] - cnt[l];
        cur[l] = excl;
        int node = c * BNODES + l;
        if (node < n) {
            off[node] = gb + excl;
            inv[node] = 1.f / fmaxf((float)cnt[l], 1.f);
        }
    }
    __syncthreads();
    for (int i = t; i < size; i += 256) {
        int vk = src[i];
        int slot = atomicAdd(&cur[vk & BMASK], 1);
        csr[gb + slot] = vk >> 9;
    }
}

// ---- gather-mean: fp8 row reads (64B = 1 line/row), f32 acc, bf16 agg out --
__global__ __launch_bounds__(256) void gather_mean_q8(
    const unsigned char* __restrict__ Xq,
    const int* __restrict__ off_f, const int* __restrict__ csr_f,
    const float* __restrict__ invf,
    const int* __restrict__ off_b, const int* __restrict__ csr_b,
    const float* __restrict__ invb,
    ushort* __restrict__ aggf, ushort* __restrict__ aggb, int n) {
    int tid = blockIdx.x * 256 + threadIdx.x;
    int node = tid >> 5;
    if (node >= n) return;
    int dir = (tid >> 4) & 1;
    int c = (tid & 15) * 4;            // element offset (4 elems = 4 bytes fp8)
    const int* off = dir ? off_b : off_f;
    const int* csr = dir ? csr_b : csr_f;
    const float* inv = dir ? invb : invf;
    ushort* agg = dir ? aggb : aggf;

    int b = off[node], en = off[node + 1];
    float ax = 0.f, ay = 0.f, az = 0.f, aw = 0.f;
    int k = b;
    for (; k + 3 < en; k += 4) {
        int n0 = csr[k], n1 = csr[k + 1], n2 = csr[k + 2], n3 = csr[k + 3];
        unsigned u0 = *reinterpret_cast<const unsigned*>(Xq + (size_t)n0 * 64 + c);
        unsigned u1 = *reinterpret_cast<const unsigned*>(Xq + (size_t)n1 * 64 + c);
        unsigned u2 = *reinterpret_cast<const unsigned*>(Xq + (size_t)n2 * 64 + c);
        unsigned u3 = *reinterpret_cast<const unsigned*>(Xq + (size_t)n3 * 64 + c);
        f32x2 l0 = __builtin_amdgcn_cvt_pk_f32_fp8((int)u0, false);
        f32x2 h0 = __builtin_amdgcn_cvt_pk_f32_fp8((int)u0, true);
        f32x2 l1 = __builtin_amdgcn_cvt_pk_f32_fp8((int)u1, false);
        f32x2 h1 = __builtin_amdgcn_cvt_pk_f32_fp8((int)u1, true);
        f32x2 l2 = __builtin_amdgcn_cvt_pk_f32_fp8((int)u2, false);
        f32x2 h2 = __builtin_amdgcn_cvt_pk_f32_fp8((int)u2, true);
        f32x2 l3 = __builtin_amdgcn_cvt_pk_f32_fp8((int)u3, false);
        f32x2 h3 = __builtin_amdgcn_cvt_pk_f32_fp8((int)u3, true);
        ax += l0.x + l1.x + l2.x + l3.x;
        ay += l0.y + l1.y + l2.y + l3.y;
        az += h0.x + h1.x + h2.x + h3.x;
        aw += h0.y + h1.y + h2.y + h3.y;
    }
    for (; k < en; k++) {
        int s = csr[k];
        unsigned u = *reinterpret_cast<const unsigned*>(Xq + (size_t)s * 64 + c);
        f32x2 lo = __builtin_amdgcn_cvt_pk_f32_fp8((int)u, false);
        f32x2 hi = __builtin_amdgcn_cvt_pk_f32_fp8((int)u, true);
        ax += lo.x; ay += lo.y; az += hi.x; aw += hi.y;
    }
    float iv = inv[node];
    ushort4 r;
    r.x = f2bf(ax * iv); r.y = f2bf(ay * iv); r.z = f2bf(az * iv); r.w = f2bf(aw * iv);
    *reinterpret_cast<ushort4*>(agg + (size_t)node * 64 + c) = r;
}

// ---------------- fused bidirectional SAGE layer (MFMA bf16) ----------------
// out = relu(0.5*(aggf@Wlf^T + aggb@Wlb^T + xb@(Wrf+Wrb)^T) + 0.5*(blf+blb))
// Outputs: bf16 (OutB) + fp8 (OutQ, via LDS repack for vector stores).
__global__ __launch_bounds__(256) void fused_sage_mfma(
    const ushort* __restrict__ Xb,
    const ushort* __restrict__ aggf, const ushort* __restrict__ aggb,
    const float* __restrict__ Wlf, const float* __restrict__ blf,
    const float* __restrict__ Wrf,
    const float* __restrict__ Wlb, const float* __restrict__ blb,
    const float* __restrict__ Wrb,
    ushort* __restrict__ OutB, unsigned char* __restrict__ OutQ, int n)
{
    __shared__ ushort sA[64][72];       // +8 bf16 pad; reused as fp8 byte buffer
    __shared__ ushort sW[3][64][72];    // bf16 weights, W[j][k] layout
    __shared__ float  sBias[64];
    const int t = threadIdx.x;
    const int base = blockIdx.x * 64;
    const int lane = t & 63;
    const int m0 = (t >> 6) * 16;       // wave's row offset
    const int lr = lane & 15;           // A row / B col / D col
    const int kb = lane >> 4;           // k-block 0..3

    // ---- stage weights (bf16) + bias, once ----
#pragma unroll
    for (int i = 0; i < 4; i++) {
        int idx4 = t + 256 * i;               // 1024 float4s = 64x64
        int row = idx4 >> 4, c4 = idx4 & 15;
        float4 w0 = *reinterpret_cast<const float4*>(Wlf + row * 64 + c4 * 4);
        float4 w1 = *reinterpret_cast<const float4*>(Wlb + row * 64 + c4 * 4);
        float4 wa = *reinterpret_cast<const float4*>(Wrf + row * 64 + c4 * 4);
        float4 wb = *reinterpret_cast<const float4*>(Wrb + row * 64 + c4 * 4);
        ushort4 o;
        o.x = f2bf(w0.x); o.y = f2bf(w0.y); o.z = f2bf(w0.z); o.w = f2bf(w0.w);
        *reinterpret_cast<ushort4*>(&sW[0][row][c4 * 4]) = o;
        o.x = f2bf(w1.x); o.y = f2bf(w1.y); o.z = f2bf(w1.z); o.w = f2bf(w1.w);
        *reinterpret_cast<ushort4*>(&sW[1][row][c4 * 4]) = o;
        o.x = f2bf(wa.x + wb.x); o.y = f2bf(wa.y + wb.y);
        o.z = f2bf(wa.z + wb.z); o.w = f2bf(wa.w + wb.w);
        *reinterpret_cast<ushort4*>(&sW[2][row][c4 * 4]) = o;
    }
    if (t < 64) sBias[t] = 0.5f * (blf[t] + blb[t]);

    f32x4 acc0 = {0.f, 0.f, 0.f, 0.f};
    f32x4 acc1 = {0.f, 0.f, 0.f, 0.f};
    f32x4 acc2 = {0.f, 0.f, 0.f, 0.f};
    f32x4 acc3 = {0.f, 0.f, 0.f, 0.f};

    for (int p = 0; p < 3; p++) {
        const ushort* src = (p == 0) ? aggf : (p == 1) ? aggb : Xb;
        __syncthreads();
        // ---- stage A tile: 64 rows x 64 bf16, 16B per thread x2 ----
#pragma unroll
        for (int i = 0; i < 2; i++) {
            int c8 = t + 256 * i;             // 512 chunks of 8 bf16
            int row = c8 >> 3, k8 = (c8 & 7) * 8;
            int node = base + row;
            uint4 v = make_uint4(0u, 0u, 0u, 0u);
            if (node < n)
                v = *reinterpret_cast<const uint4*>(src + (size_t)node * 64 + k8);
            *reinterpret_cast<uint4*>(&sA[row][k8]) = v;
        }
        __syncthreads();
        // ---- MFMA: 2 k-halves x 4 col-blocks ----
#pragma unroll
        for (int kh = 0; kh < 2; kh++) {
            bf16x8 a = *(const bf16x8*)(&sA[m0 + lr][kh * 32 + kb * 8]);
            bf16x8 b0 = *(const bf16x8*)(&sW[p][0 * 16 + lr][kh * 32 + kb * 8]);
            bf16x8 b1 = *(const bf16x8*)(&sW[p][1 * 16 + lr][kh * 32 + kb * 8]);
            bf16x8 b2 = *(const bf16x8*)(&sW[p][2 * 16 + lr][kh * 32 + kb * 8]);
            bf16x8 b3 = *(const bf16x8*)(&sW[p][3 * 16 + lr][kh * 32 + kb * 8]);
            acc0 = __builtin_amdgcn_mfma_f32_16x16x32_bf16(a, b0, acc0, 0, 0, 0);
            acc1 = __builtin_amdgcn_mfma_f32_16x16x32_bf16(a, b1, acc1, 0, 0, 0);
            acc2 = __builtin_amdgcn_mfma_f32_16x16x32_bf16(a, b2, acc2, 0, 0, 0);
            acc3 = __builtin_amdgcn_mfma_f32_16x16x32_bf16(a, b3, acc3, 0, 0, 0);
        }
    }
    // ---- epilogue: bias + relu; bf16 scalar stores + fp8 via LDS repack ----
    __syncthreads();   // all waves done reading sA before repurposing
    unsigned char* sQ = reinterpret_cast<unsigned char*>(&sA[0][0]);  // [64][80]
#pragma unroll
    for (int b = 0; b < 4; b++) {
        int j = lr + 16 * b;
        float bias = sBias[j];
        f32x4 ac = (b == 0) ? acc0 : (b == 1) ? acc1 : (b == 2) ? acc2 : acc3;
#pragma unroll
        for (int i = 0; i < 4; i++) {
            int row = m0 + kb * 4 + i;
            float v = 0.5f * ac[i] + bias;
            v = v > 0.f ? v : 0.f;
            if (base + row < n) OutB[(size_t)(base + row) * 64 + j] = f2bf(v);
            sQ[row * 80 + j] = enc1fp8(v);
        }
    }
    __syncthreads();
    {
        int row = t >> 2, c16 = (t & 3) * 16;
        if (base + row < n) {
            uint4 v = *reinterpret_cast<const uint4*>(&sQ[row * 80 + c16]);
            *reinterpret_cast<uint4*>(OutQ + (size_t)(base + row) * 64 + c16) = v;
        }
    }
}

// ---- pooling: sorted batch -> register accumulate, flush on graph change ---
__global__ __launch_bounds__(256) void pool_partial(const ushort* __restrict__ H,
                                                    const int* __restrict__ batch,
                                                    float* __restrict__ psum,
                                                    float* __restrict__ pcnt, int n) {
    __shared__ float ls[GG * 64];
    __shared__ float lc[GG];
    int t = threadIdx.x;
    for (int i = t; i < GG * 64; i += 256) ls[i] = 0.f;
    for (int i = t; i < GG; i += 256) lc[i] = 0.f;
    __syncthreads();
    int chunk = (n + gridDim.x - 1) / gridDim.x;
    int base = blockIdx.x * chunk;
    int end = base + chunk; if (end > n) end = n;
    int f = t & 63, r = t >> 6;
    float acc = 0.f; int cnt = 0; int curg = -1;
    for (int node = base + r; node < end; node += 4) {
        int g = batch[node];
        if (g != curg) {
            if (curg >= 0) {
                atomicAdd(&ls[curg * 64 + f], acc);
                if (f == 0) atomicAdd(&lc[curg], (float)cnt);
            }
            curg = g; acc = 0.f; cnt = 0;
        }
        acc += bf2f(H[(size_t)node * 64 + f]);
        cnt++;
    }
    if (curg >= 0) {
        atomicAdd(&ls[curg * 64 + f], acc);
        if (f == 0) atomicAdd(&lc[curg], (float)cnt);
    }
    __syncthreads();
    for (int i = t; i < GG * 64; i += 256) {
        float v = ls[i];
        if (v != 0.f) atomicAdd(&psum[i], v);
    }
    for (int i = t; i < GG; i += 256) {
        float v = lc[i];
        if (v != 0.f) atomicAdd(&pcnt[i], v);
    }
}

// ---------------- head ----------------
__global__ __launch_bounds__(256) void pool_final(const float* __restrict__ psum,
                                                  const float* __restrict__ pcnt,
                                                  const float* __restrict__ PW,
                                                  const float* __restrict__ Pb,
                                                  float* __restrict__ out) {
    int t = blockIdx.x * 256 + threadIdx.x;
    int g = t >> 4, o = t & 15;
    if (g >= GG) return;
    float inv = 1.f / fmaxf(pcnt[g], 1.f);
    float acc = 0.f;
#pragma unroll 8
    for (int k = 0; k < 64; k++) acc += psum[g * 64 + k] * PW[o * 64 + k];
    out[t] = acc * inv + Pb[o];
}

extern "C" void kernel_launch(void* const* d_in, const int* in_sizes, int n_in,
                              void* d_out, int out_size, void* d_ws, size_t ws_size,
                              hipStream_t stream) {
    const float* x      = (const float*)d_in[0];
    const int*   ei     = (const int*)d_in[1];
    const int*   batch  = (const int*)d_in[2];
    const float* l0f_Wl = (const float*)d_in[4];
    const float* l0f_bl = (const float*)d_in[5];
    const float* l0f_Wr = (const float*)d_in[6];
    const float* l0b_Wl = (const float*)d_in[7];
    const float* l0b_bl = (const float*)d_in[8];
    const float* l0b_Wr = (const float*)d_in[9];
    const float* l1f_Wl = (const float*)d_in[10];
    const float* l1f_bl = (const float*)d_in[11];
    const float* l1f_Wr = (const float*)d_in[12];
    const float* l1b_Wl = (const float*)d_in[13];
    const float* l1b_bl = (const float*)d_in[14];
    const float* l1b_Wr = (const float*)d_in[15];
    const float* pred_W = (const float*)d_in[16];
    const float* pred_b = (const float*)d_in[17];

    const int n = in_sizes[0] / 64;
    const int e = in_sizes[1] / 2;
    const int nb = (n + BNODES - 1) >> BSHIFT;   // <= 256 required

    // ---- workspace layout (int elements) ----
    int* ws = (int*)d_ws;
    size_t o = 0;
    int*   gcurF = ws + o;  o += (size_t)nb * PADI;      // zeroed
    int*   gcurB = ws + o;  o += (size_t)nb * PADI;      // zeroed
    float* psum  = (float*)(ws + o); o += GG * 64;       // zeroed
    float* pcnt  = (float*)(ws + o); o += GG;            // zeroed
    size_t zcount = o;
    int*   gbaseF = ws + o; o += nb + 1;
    int*   gbaseB = ws + o; o += nb + 1;
    int*   off_f = ws + o;  o += n + 1;
    int*   off_b = ws + o;  o += n + 1;
    float* invf  = (float*)(ws + o); o += n;
    float* invb  = (float*)(ws + o); o += n;
    int*   csr_f = ws + o;  o += e;
    int*   csr_b = ws + o;  o += e;
    o = (o + 15) & ~(size_t)15;                          // 64B align
    int*   bktF  = ws + o;  o += (size_t)nb * CAP;       // packed entries
    int*   bktB  = ws + o;  o += (size_t)nb * CAP;
    ushort* xb    = (ushort*)(ws + o); o += (size_t)n * 32;  // [n][64] bf16 (x->h0->h1)
    ushort* aggfb = (ushort*)(ws + o); o += (size_t)n * 32;  // [n][64] bf16
    ushort* aggbb = (ushort*)(ws + o); o += (size_t)n * 32;  // [n][64] bf16
    o = (o + 15) & ~(size_t)15;                          // 64B align for fp8 rows
    unsigned* xq  = (unsigned*)(ws + o); o += (size_t)n * 16; // [n][64] fp8 (x->h0->h1)

    zero_ws<<<((int)zcount + 255) / 256, 256, 0, stream>>>(ws, (int)zcount);

    // ---- CSR build via bucket counting-sort ----
    to_bf16_fp8<<<((size_t)n * 16 + 255) / 256, 256, 0, stream>>>(x, xb, xq, n * 16);
    bucket_scatter<<<(e + 2047) / 2048, 256, 2 * nb * sizeof(int), stream>>>(
        ei, gcurF, gcurB, bktF, bktB, e, nb);
    bucket_scan<<<2, 256, 0, stream>>>(gcurF, gcurB, gbaseF, gbaseB,
                                       off_f, off_b, nb, n, e);
    bucket_csr<<<nb, 256, 0, stream>>>(bktF, gcurF, gbaseF, csr_f, off_f, invf, n, nb);
    bucket_csr<<<nb, 256, 0, stream>>>(bktB, gcurB, gbaseB, csr_b, off_b, invb, n, nb);

    // layer 0: fp8 gather -> bf16 agg; MFMA sage -> h0 (bf16 xb + fp8 xq, in place)
    gather_mean_q8<<<((size_t)n * 32 + 255) / 256, 256, 0, stream>>>(
        (const unsigned char*)xq, off_f, csr_f, invf, off_b, csr_b, invb,
        aggfb, aggbb, n);
    fused_sage_mfma<<<(n + 63) / 64, 256, 0, stream>>>(xb, aggfb, aggbb,
        l0f_Wl, l0f_bl, l0f_Wr, l0b_Wl, l0b_bl, l0b_Wr,
        xb, (unsigned char*)xq, n);

    // layer 1
    gather_mean_q8<<<((size_t)n * 32 + 255) / 256, 256, 0, stream>>>(
        (const unsigned char*)xq, off_f, csr_f, invf, off_b, csr_b, invb,
        aggfb, aggbb, n);
    fused_sage_mfma<<<(n + 63) / 64, 256, 0, stream>>>(xb, aggfb, aggbb,
        l1f_Wl, l1f_bl, l1f_Wr, l1b_Wl, l1b_bl, l1b_Wr,
        xb, (unsigned char*)xq, n);

    // pooling + head
    pool_partial<<<256, 256, 0, stream>>>(xb, batch, psum, pcnt, n);
    pool_final<<<8, 256, 0, stream>>>(psum, pcnt, pred_W, pred_b, (float*)d_out);
}

// Round 16
// 213.427 us; speedup vs baseline: 1.7368x; 1.0973x over previous
//
#include <hip/hip_runtime.h>
#include <hip/hip_bf16.h>

#define GG 128      // num_graphs (static in problem)
#define BSHIFT 9    // 512 nodes per bucket
#define BMASK 511
#define BNODES 512
#define PADI 16     // ints per padded global bucket counter (one 64B line each)
#define CAP 8192    // bucket capacity (mean ~5100 at n=100k,e=1M)

typedef __attribute__((ext_vector_type(8))) short bf16x8;
typedef __attribute__((ext_vector_type(4))) float f32x4;
typedef __attribute__((ext_vector_type(2))) float f32x2;
typedef __attribute__((ext_vector_type(4))) int i32x4;

// ---------------- bf16 helpers (RNE) ----------------
__device__ __forceinline__ ushort f2bf(float f) {
    union { float f; unsigned u; } v; v.f = f;
    unsigned r = v.u + 0x7FFF + ((v.u >> 16) & 1);
    return (ushort)(r >> 16);
}
__device__ __forceinline__ float bf2f(ushort s) {
    union { unsigned u; float f; } v; v.u = ((unsigned)s) << 16;
    return v.f;
}

// ---------------- fp8 helpers (native gfx950 converters) ----------------
__device__ __forceinline__ unsigned enc4fp8(float v0, float v1, float v2, float v3) {
    int p = __builtin_amdgcn_cvt_pk_fp8_f32(v0, v1, 0, false);
    p = __builtin_amdgcn_cvt_pk_fp8_f32(v2, v3, p, true);
    return (unsigned)p;
}
__device__ __forceinline__ unsigned char enc1fp8(float v) {
    return (unsigned char)(__builtin_amdgcn_cvt_pk_fp8_f32(v, v, 0, false) & 0xFF);
}

// ------- prep: zero counters + f32 -> bf16 + fp8 rows (fused) ---------------
__global__ __launch_bounds__(256) void prep(const float* __restrict__ X,
                                            ushort* __restrict__ Xb,
                                            unsigned* __restrict__ Xq,
                                            int n4, int* __restrict__ z, int zc) {
    int i = blockIdx.x * 256 + threadIdx.x;
    if (i < zc) z[i] = 0;
    if (i >= n4) return;
    float4 v = reinterpret_cast<const float4*>(X)[i];
    ushort4 o;
    o.x = f2bf(v.x); o.y = f2bf(v.y); o.z = f2bf(v.z); o.w = f2bf(v.w);
    reinterpret_cast<ushort4*>(Xb)[i] = o;
    Xq[i] = enc4fp8(v.x, v.y, v.z, v.w);
}

// ------- phase A: bucket edges by coarse key, PACKED entries ----------------
// entry = (neighbor_value << 9) | (key & 511); value < 2^17 (n <= 131072)
__global__ __launch_bounds__(256) void bucket_scatter(
    const int* __restrict__ ei,
    int* __restrict__ gcurF, int* __restrict__ gcurB,
    int* __restrict__ bktF, int* __restrict__ bktB,
    int e, int nb) {
    extern __shared__ int lds[];             // cntF[nb], cntB[nb]
    int* cntF = lds;
    int* cntB = lds + nb;
    int t = threadIdx.x;
    for (int i = t; i < 2 * nb; i += 256) lds[i] = 0;
    __syncthreads();
    int base = blockIdx.x * 2048;
    int i0 = base + t * 8;
    int s[8], d[8], rf[8], rb[8];
    if (i0 + 8 <= e && (e & 3) == 0) {       // vector path (2x int4 per side)
        i32x4 sa = *reinterpret_cast<const i32x4*>(ei + i0);
        i32x4 sb = *reinterpret_cast<const i32x4*>(ei + i0 + 4);
        i32x4 da = *reinterpret_cast<const i32x4*>(ei + e + i0);
        i32x4 db = *reinterpret_cast<const i32x4*>(ei + e + i0 + 4);
        s[0]=sa.x; s[1]=sa.y; s[2]=sa.z; s[3]=sa.w;
        s[4]=sb.x; s[5]=sb.y; s[6]=sb.z; s[7]=sb.w;
        d[0]=da.x; d[1]=da.y; d[2]=da.z; d[3]=da.w;
        d[4]=db.x; d[5]=db.y; d[6]=db.z; d[7]=db.w;
    } else {
#pragma unroll
        for (int k = 0; k < 8; k++) {
            int idx = i0 + k;
            s[k] = (idx < e) ? ei[idx] : 0;
            d[k] = (idx < e) ? ei[e + idx] : 0;
        }
    }
#pragma unroll
    for (int k = 0; k < 8; k++) {
        if (i0 + k < e) {
            rf[k] = atomicAdd(&cntF[d[k] >> BSHIFT], 1);
            rb[k] = atomicAdd(&cntB[s[k] >> BSHIFT], 1);
        }
    }
    __syncthreads();
    for (int c = t; c < nb; c += 256) {
        int vF = cntF[c];
        if (vF) cntF[c] = atomicAdd(&gcurF[(size_t)c * PADI], vF);
        int vB = cntB[c];
        if (vB) cntB[c] = atomicAdd(&gcurB[(size_t)c * PADI], vB);
    }
    __syncthreads();
#pragma unroll
    for (int k = 0; k < 8; k++) {
        if (i0 + k < e) {
            int cF = d[k] >> BSHIFT;
            int slotF = cntF[cF] + rf[k];
            if (slotF < CAP) bktF[(size_t)cF * CAP + slotF] = (s[k] << 9) | (d[k] & BMASK);
            int cB = s[k] >> BSHIFT;
            int slotB = cntB[cB] + rb[k];
            if (slotB < CAP) bktB[(size_t)cB * CAP + slotB] = (d[k] << 9) | (s[k] & BMASK);
        }
    }
}

// ------- phase B: per-bucket CSR finalize, both dirs, inline base scan ------
__global__ __launch_bounds__(256) void bucket_csr_all(
    const int* __restrict__ bktF, const int* __restrict__ bktB,
    const int* __restrict__ gcurF, const int* __restrict__ gcurB,
    int* __restrict__ csr_f, int* __restrict__ csr_b,
    int* __restrict__ off_f, int* __restrict__ off_b,
    float* __restrict__ invf, float* __restrict__ invb,
    int n, int nb, int e) {
    const int dir = blockIdx.y;
    const int* bkt = dir ? bktB : bktF;
    const int* gcur = dir ? gcurB : gcurF;
    int* csr = dir ? csr_b : csr_f;
    int* off = dir ? off_b : off_f;
    float* inv = dir ? invb : invf;
    const int c = blockIdx.x;
    const int t = threadIdx.x;

    // ---- inline exclusive scan of bucket sizes (nb <= 256) -> gb ----
    __shared__ int sb[2][256];
    int v = (t < nb) ? min(gcur[(size_t)t * PADI], CAP) : 0;
    sb[0][t] = v;
    __syncthreads();
    int pq = 0;
    for (int ofs = 1; ofs < 256; ofs <<= 1) {
        int u = sb[pq][t];
        if (t >= ofs) u += sb[pq][t - ofs];
        sb[pq ^ 1][t] = u;
        __syncthreads();
        pq ^= 1;
    }
    int size = min(gcur[(size_t)c * PADI], CAP);
    int gb = sb[pq][c] - size;               // exclusive prefix at c
    if (t == 0 && c == 0) off[n] = e;

    // ---- per-bucket histogram + scan + place ----
    __shared__ int cnt[BNODES];
    __shared__ int cur[BNODES];
    __shared__ int sc[2][BNODES];
    const int* src = bkt + (size_t)c * CAP;
    for (int l = t; l < BNODES; l += 256) cnt[l] = 0;
    __syncthreads();
    for (int i = t; i < size; i += 256)
        atomicAdd(&cnt[src[i] & BMASK], 1);
    __syncthreads();
    for (int l = t; l < BNODES; l += 256) sc[0][l] = cnt[l];
    __syncthreads();
    int pp = 0;
    for (int ofs = 1; ofs < BNODES; ofs <<= 1) {
        for (int l = t; l < BNODES; l += 256) {
            int u = sc[pp][l];
            if (l >= ofs) u += sc[pp][l - ofs];
            sc[pp ^ 1][l] = u;
        }
        __syncthreads();
        pp ^= 1;
    }
    for (int l = t; l < BNODES; l += 256) {
        int excl = sc[pp][l] - cnt[l];
        cur[l] = excl;
        int node = c * BNODES + l;
        if (node < n) {
            off[node] = gb + excl;
            inv[node] = 1.f / fmaxf((float)cnt[l], 1.f);
        }
    }
    __syncthreads();
    for (int i = t; i < size; i += 256) {
        int vk = src[i];
        int slot = atomicAdd(&cur[vk & BMASK], 1);
        csr[gb + slot] = vk >> 9;
    }
}

// ---- gather-mean: fp8 row reads (64B = 1 line/row), f32 acc, bf16 agg out --
__global__ __launch_bounds__(256) void gather_mean_q8(
    const unsigned char* __restrict__ Xq,
    const int* __restrict__ off_f, const int* __restrict__ csr_f,
    const float* __restrict__ invf,
    const int* __restrict__ off_b, const int* __restrict__ csr_b,
    const float* __restrict__ invb,
    ushort* __restrict__ aggf, ushort* __restrict__ aggb, int n) {
    int tid = blockIdx.x * 256 + threadIdx.x;
    int node = tid >> 5;
    if (node >= n) return;
    int dir = (tid >> 4) & 1;
    int c = (tid & 15) * 4;            // element offset (4 elems = 4 bytes fp8)
    const int* off = dir ? off_b : off_f;
    const int* csr = dir ? csr_b : csr_f;
    const float* inv = dir ? invb : invf;
    ushort* agg = dir ? aggb : aggf;

    int b = off[node], en = off[node + 1];
    float ax = 0.f, ay = 0.f, az = 0.f, aw = 0.f;
    int k = b;
    for (; k + 3 < en; k += 4) {
        int n0 = csr[k], n1 = csr[k + 1], n2 = csr[k + 2], n3 = csr[k + 3];
        unsigned u0 = *reinterpret_cast<const unsigned*>(Xq + (size_t)n0 * 64 + c);
        unsigned u1 = *reinterpret_cast<const unsigned*>(Xq + (size_t)n1 * 64 + c);
        unsigned u2 = *reinterpret_cast<const unsigned*>(Xq + (size_t)n2 * 64 + c);
        unsigned u3 = *reinterpret_cast<const unsigned*>(Xq + (size_t)n3 * 64 + c);
        f32x2 l0 = __builtin_amdgcn_cvt_pk_f32_fp8((int)u0, false);
        f32x2 h0 = __builtin_amdgcn_cvt_pk_f32_fp8((int)u0, true);
        f32x2 l1 = __builtin_amdgcn_cvt_pk_f32_fp8((int)u1, false);
        f32x2 h1 = __builtin_amdgcn_cvt_pk_f32_fp8((int)u1, true);
        f32x2 l2 = __builtin_amdgcn_cvt_pk_f32_fp8((int)u2, false);
        f32x2 h2 = __builtin_amdgcn_cvt_pk_f32_fp8((int)u2, true);
        f32x2 l3 = __builtin_amdgcn_cvt_pk_f32_fp8((int)u3, false);
        f32x2 h3 = __builtin_amdgcn_cvt_pk_f32_fp8((int)u3, true);
        ax += l0.x + l1.x + l2.x + l3.x;
        ay += l0.y + l1.y + l2.y + l3.y;
        az += h0.x + h1.x + h2.x + h3.x;
        aw += h0.y + h1.y + h2.y + h3.y;
    }
    for (; k < en; k++) {
        int s = csr[k];
        unsigned u = *reinterpret_cast<const unsigned*>(Xq + (size_t)s * 64 + c);
        f32x2 lo = __builtin_amdgcn_cvt_pk_f32_fp8((int)u, false);
        f32x2 hi = __builtin_amdgcn_cvt_pk_f32_fp8((int)u, true);
        ax += lo.x; ay += lo.y; az += hi.x; aw += hi.y;
    }
    float iv = inv[node];
    ushort4 r;
    r.x = f2bf(ax * iv); r.y = f2bf(ay * iv); r.z = f2bf(az * iv); r.w = f2bf(aw * iv);
    *reinterpret_cast<ushort4*>(agg + (size_t)node * 64 + c) = r;
}

// ---------------- fused bidirectional SAGE layer (MFMA bf16) ----------------
// out = relu(0.5*(aggf@Wlf^T + aggb@Wlb^T + xb@(Wrf+Wrb)^T) + 0.5*(blf+blb))
// Outputs: bf16 (OutB) + fp8 (OutQ, via LDS repack for vector stores).
__global__ __launch_bounds__(256) void fused_sage_mfma(
    const ushort* __restrict__ Xb,
    const ushort* __restrict__ aggf, const ushort* __restrict__ aggb,
    const float* __restrict__ Wlf, const float* __restrict__ blf,
    const float* __restrict__ Wrf,
    const float* __restrict__ Wlb, const float* __restrict__ blb,
    const float* __restrict__ Wrb,
    ushort* __restrict__ OutB, unsigned char* __restrict__ OutQ, int n)
{
    __shared__ ushort sA[64][72];       // +8 bf16 pad; reused as fp8 byte buffer
    __shared__ ushort sW[3][64][72];    // bf16 weights, W[j][k] layout
    __shared__ float  sBias[64];
    const int t = threadIdx.x;
    const int base = blockIdx.x * 64;
    const int lane = t & 63;
    const int m0 = (t >> 6) * 16;       // wave's row offset
    const int lr = lane & 15;           // A row / B col / D col
    const int kb = lane >> 4;           // k-block 0..3

    // ---- stage weights (bf16) + bias, once ----
#pragma unroll
    for (int i = 0; i < 4; i++) {
        int idx4 = t + 256 * i;               // 1024 float4s = 64x64
        int row = idx4 >> 4, c4 = idx4 & 15;
        float4 w0 = *reinterpret_cast<const float4*>(Wlf + row * 64 + c4 * 4);
        float4 w1 = *reinterpret_cast<const float4*>(Wlb + row * 64 + c4 * 4);
        float4 wa = *reinterpret_cast<const float4*>(Wrf + row * 64 + c4 * 4);
        float4 wb = *reinterpret_cast<const float4*>(Wrb + row * 64 + c4 * 4);
        ushort4 o;
        o.x = f2bf(w0.x); o.y = f2bf(w0.y); o.z = f2bf(w0.z); o.w = f2bf(w0.w);
        *reinterpret_cast<ushort4*>(&sW[0][row][c4 * 4]) = o;
        o.x = f2bf(w1.x); o.y = f2bf(w1.y); o.z = f2bf(w1.z); o.w = f2bf(w1.w);
        *reinterpret_cast<ushort4*>(&sW[1][row][c4 * 4]) = o;
        o.x = f2bf(wa.x + wb.x); o.y = f2bf(wa.y + wb.y);
        o.z = f2bf(wa.z + wb.z); o.w = f2bf(wa.w + wb.w);
        *reinterpret_cast<ushort4*>(&sW[2][row][c4 * 4]) = o;
    }
    if (t < 64) sBias[t] = 0.5f * (blf[t] + blb[t]);

    f32x4 acc0 = {0.f, 0.f, 0.f, 0.f};
    f32x4 acc1 = {0.f, 0.f, 0.f, 0.f};
    f32x4 acc2 = {0.f, 0.f, 0.f, 0.f};
    f32x4 acc3 = {0.f, 0.f, 0.f, 0.f};

    for (int p = 0; p < 3; p++) {
        const ushort* src = (p == 0) ? aggf : (p == 1) ? aggb : Xb;
        __syncthreads();
        // ---- stage A tile: 64 rows x 64 bf16, 16B per thread x2 ----
#pragma unroll
        for (int i = 0; i < 2; i++) {
            int c8 = t + 256 * i;             // 512 chunks of 8 bf16
            int row = c8 >> 3, k8 = (c8 & 7) * 8;
            int node = base + row;
            uint4 v = make_uint4(0u, 0u, 0u, 0u);
            if (node < n)
                v = *reinterpret_cast<const uint4*>(src + (size_t)node * 64 + k8);
            *reinterpret_cast<uint4*>(&sA[row][k8]) = v;
        }
        __syncthreads();
        // ---- MFMA: 2 k-halves x 4 col-blocks ----
#pragma unroll
        for (int kh = 0; kh < 2; kh++) {
            bf16x8 a = *(const bf16x8*)(&sA[m0 + lr][kh * 32 + kb * 8]);
            bf16x8 b0 = *(const bf16x8*)(&sW[p][0 * 16 + lr][kh * 32 + kb * 8]);
            bf16x8 b1 = *(const bf16x8*)(&sW[p][1 * 16 + lr][kh * 32 + kb * 8]);
            bf16x8 b2 = *(const bf16x8*)(&sW[p][2 * 16 + lr][kh * 32 + kb * 8]);
            bf16x8 b3 = *(const bf16x8*)(&sW[p][3 * 16 + lr][kh * 32 + kb * 8]);
            acc0 = __builtin_amdgcn_mfma_f32_16x16x32_bf16(a, b0, acc0, 0, 0, 0);
            acc1 = __builtin_amdgcn_mfma_f32_16x16x32_bf16(a, b1, acc1, 0, 0, 0);
            acc2 = __builtin_amdgcn_mfma_f32_16x16x32_bf16(a, b2, acc2, 0, 0, 0);
            acc3 = __builtin_amdgcn_mfma_f32_16x16x32_bf16(a, b3, acc3, 0, 0, 0);
        }
    }
    // ---- epilogue: bias + relu; bf16 scalar stores + fp8 via LDS repack ----
    __syncthreads();   // all waves done reading sA before repurposing
    unsigned char* sQ = reinterpret_cast<unsigned char*>(&sA[0][0]);  // [64][80]
#pragma unroll
    for (int b = 0; b < 4; b++) {
        int j = lr + 16 * b;
        float bias = sBias[j];
        f32x4 ac = (b == 0) ? acc0 : (b == 1) ? acc1 : (b == 2) ? acc2 : acc3;
#pragma unroll
        for (int i = 0; i < 4; i++) {
            int row = m0 + kb * 4 + i;
            float v = 0.5f * ac[i] + bias;
            v = v > 0.f ? v : 0.f;
            if (base + row < n) OutB[(size_t)(base + row) * 64 + j] = f2bf(v);
            sQ[row * 80 + j] = enc1fp8(v);
        }
    }
    __syncthreads();
    {
        int row = t >> 2, c16 = (t & 3) * 16;
        if (base + row < n) {
            uint4 v = *reinterpret_cast<const uint4*>(&sQ[row * 80 + c16]);
            *reinterpret_cast<uint4*>(OutQ + (size_t)(base + row) * 64 + c16) = v;
        }
    }
}

// ---- pooling: sorted batch -> register accumulate, flush on graph change ---
__global__ __launch_bounds__(256) void pool_partial(const ushort* __restrict__ H,
                                                    const int* __restrict__ batch,
                                                    float* __restrict__ psum,
                                                    float* __restrict__ pcnt, int n) {
    __shared__ float ls[GG * 64];
    __shared__ float lc[GG];
    int t = threadIdx.x;
    for (int i = t; i < GG * 64; i += 256) ls[i] = 0.f;
    for (int i = t; i < GG; i += 256) lc[i] = 0.f;
    __syncthreads();
    int chunk = (n + gridDim.x - 1) / gridDim.x;
    int base = blockIdx.x * chunk;
    int end = base + chunk; if (end > n) end = n;
    int f = t & 63, r = t >> 6;
    float acc = 0.f; int cnt = 0; int curg = -1;
    for (int node = base + r; node < end; node += 4) {
        int g = batch[node];
        if (g != curg) {
            if (curg >= 0) {
                atomicAdd(&ls[curg * 64 + f], acc);
                if (f == 0) atomicAdd(&lc[curg], (float)cnt);
            }
            curg = g; acc = 0.f; cnt = 0;
        }
        acc += bf2f(H[(size_t)node * 64 + f]);
        cnt++;
    }
    if (curg >= 0) {
        atomicAdd(&ls[curg * 64 + f], acc);
        if (f == 0) atomicAdd(&lc[curg], (float)cnt);
    }
    __syncthreads();
    for (int i = t; i < GG * 64; i += 256) {
        float v = ls[i];
        if (v != 0.f) atomicAdd(&psum[i], v);
    }
    for (int i = t; i < GG; i += 256) {
        float v = lc[i];
        if (v != 0.f) atomicAdd(&pcnt[i], v);
    }
}

// ---------------- head ----------------
__global__ __launch_bounds__(256) void pool_final(const float* __restrict__ psum,
                                                  const float* __restrict__ pcnt,
                                                  const float* __restrict__ PW,
                                                  const float* __restrict__ Pb,
                                                  float* __restrict__ out) {
    int t = blockIdx.x * 256 + threadIdx.x;
    int g = t >> 4, o = t & 15;
    if (g >= GG) return;
    float inv = 1.f / fmaxf(pcnt[g], 1.f);
    float acc = 0.f;
#pragma unroll 8
    for (int k = 0; k < 64; k++) acc += psum[g * 64 + k] * PW[o * 64 + k];
    out[t] = acc * inv + Pb[o];
}

extern "C" void kernel_launch(void* const* d_in, const int* in_sizes, int n_in,
                              void* d_out, int out_size, void* d_ws, size_t ws_size,
                              hipStream_t stream) {
    const float* x      = (const float*)d_in[0];
    const int*   ei     = (const int*)d_in[1];
    const int*   batch  = (const int*)d_in[2];
    const float* l0f_Wl = (const float*)d_in[4];
    const float* l0f_bl = (const float*)d_in[5];
    const float* l0f_Wr = (const float*)d_in[6];
    const float* l0b_Wl = (const float*)d_in[7];
    const float* l0b_bl = (const float*)d_in[8];
    const float* l0b_Wr = (const float*)d_in[9];
    const float* l1f_Wl = (const float*)d_in[10];
    const float* l1f_bl = (const float*)d_in[11];
    const float* l1f_Wr = (const float*)d_in[12];
    const float* l1b_Wl = (const float*)d_in[13];
    const float* l1b_bl = (const float*)d_in[14];
    const float* l1b_Wr = (const float*)d_in[15];
    const float* pred_W = (const float*)d_in[16];
    const float* pred_b = (const float*)d_in[17];

    const int n = in_sizes[0] / 64;
    const int e = in_sizes[1] / 2;
    const int nb = (n + BNODES - 1) >> BSHIFT;   // <= 256 required

    // ---- workspace layout (int elements) ----
    int* ws = (int*)d_ws;
    size_t o = 0;
    int*   gcurF = ws + o;  o += (size_t)nb * PADI;      // zeroed
    int*   gcurB = ws + o;  o += (size_t)nb * PADI;      // zeroed
    float* psum  = (float*)(ws + o); o += GG * 64;       // zeroed
    float* pcnt  = (float*)(ws + o); o += GG;            // zeroed
    size_t zcount = o;
    int*   off_f = ws + o;  o += n + 1;
    int*   off_b = ws + o;  o += n + 1;
    float* invf  = (float*)(ws + o); o += n;
    float* invb  = (float*)(ws + o); o += n;
    int*   csr_f = ws + o;  o += e;
    int*   csr_b = ws + o;  o += e;
    o = (o + 15) & ~(size_t)15;                          // 64B align
    int*   bktF  = ws + o;  o += (size_t)nb * CAP;       // packed entries
    int*   bktB  = ws + o;  o += (size_t)nb * CAP;
    ushort* xb    = (ushort*)(ws + o); o += (size_t)n * 32;  // [n][64] bf16 (x->h0->h1)
    ushort* aggfb = (ushort*)(ws + o); o += (size_t)n * 32;  // [n][64] bf16
    ushort* aggbb = (ushort*)(ws + o); o += (size_t)n * 32;  // [n][64] bf16
    o = (o + 15) & ~(size_t)15;                          // 64B align for fp8 rows
    unsigned* xq  = (unsigned*)(ws + o); o += (size_t)n * 16; // [n][64] fp8 (x->h0->h1)

    // ---- prep (zero + convert), then CSR build via bucket counting-sort ----
    prep<<<(n * 16 + 255) / 256, 256, 0, stream>>>(x, xb, xq, n * 16, ws, (int)zcount);
    bucket_scatter<<<(e + 2047) / 2048, 256, 2 * nb * sizeof(int), stream>>>(
        ei, gcurF, gcurB, bktF, bktB, e, nb);
    bucket_csr_all<<<dim3(nb, 2), 256, 0, stream>>>(
        bktF, bktB, gcurF, gcurB, csr_f, csr_b, off_f, off_b, invf, invb, n, nb, e);

    // layer 0: fp8 gather -> bf16 agg; MFMA sage -> h0 (bf16 xb + fp8 xq)
    gather_mean_q8<<<((size_t)n * 32 + 255) / 256, 256, 0, stream>>>(
        (const unsigned char*)xq, off_f, csr_f, invf, off_b, csr_b, invb,
        aggfb, aggbb, n);
    fused_sage_mfma<<<(n + 63) / 64, 256, 0, stream>>>(xb, aggfb, aggbb,
        l0f_Wl, l0f_bl, l0f_Wr, l0b_Wl, l0b_bl, l0b_Wr,
        xb, (unsigned char*)xq, n);

    // layer 1
    gather_mean_q8<<<((size_t)n * 32 + 255) / 256, 256, 0, stream>>>(
        (const unsigned char*)xq, off_f, csr_f, invf, off_b, csr_b, invb,
        aggfb, aggbb, n);
    fused_sage_mfma<<<(n + 63) / 64, 256, 0, stream>>>(xb, aggfb, aggbb,
        l1f_Wl, l1f_bl, l1f_Wr, l1b_Wl, l1b_bl, l1b_Wr,
        xb, (unsigned char*)xq, n);

    // pooling + head
    pool_partial<<<256, 256, 0, stream>>>(xb, batch, psum, pcnt, n);
    pool_final<<<8, 256, 0, stream>>>(psum, pcnt, pred_W, pred_b, (float*)d_out);
}

// Round 17
// 207.270 us; speedup vs baseline: 1.7884x; 1.0297x over previous
//
#include <hip/hip_runtime.h>
#include <hip/hip_bf16.h>

#define GG 128      // num_graphs (static in problem)
#define BSHIFT 9    // 512 nodes per bucket
#define BMASK 511
#define BNODES 512
#define PADI 16     // ints per padded global bucket counter (one 64B line each)
#define CAP 8192    // bucket capacity (mean ~5100 at n=100k,e=1M)

typedef __attribute__((ext_vector_type(8))) short bf16x8;
typedef __attribute__((ext_vector_type(4))) float f32x4;
typedef __attribute__((ext_vector_type(2))) float f32x2;
typedef __attribute__((ext_vector_type(4))) int i32x4;

// ---------------- bf16 helpers (RNE) ----------------
__device__ __forceinline__ ushort f2bf(float f) {
    union { float f; unsigned u; } v; v.f = f;
    unsigned r = v.u + 0x7FFF + ((v.u >> 16) & 1);
    return (ushort)(r >> 16);
}
__device__ __forceinline__ float bf2f(ushort s) {
    union { unsigned u; float f; } v; v.u = ((unsigned)s) << 16;
    return v.f;
}

// ---------------- fp8 helpers (native gfx950 converters) ----------------
__device__ __forceinline__ unsigned enc4fp8(float v0, float v1, float v2, float v3) {
    int p = __builtin_amdgcn_cvt_pk_fp8_f32(v0, v1, 0, false);
    p = __builtin_amdgcn_cvt_pk_fp8_f32(v2, v3, p, true);
    return (unsigned)p;
}
__device__ __forceinline__ unsigned char enc1fp8(float v) {
    return (unsigned char)(__builtin_amdgcn_cvt_pk_fp8_f32(v, v, 0, false) & 0xFF);
}

// ------- prep: zero counters + f32 -> bf16 + fp8 rows (fused) ---------------
__global__ __launch_bounds__(256) void prep(const float* __restrict__ X,
                                            ushort* __restrict__ Xb,
                                            unsigned* __restrict__ Xq,
                                            int n4, int* __restrict__ z, int zc) {
    int i = blockIdx.x * 256 + threadIdx.x;
    if (i < zc) z[i] = 0;
    if (i >= n4) return;
    float4 v = reinterpret_cast<const float4*>(X)[i];
    ushort4 o;
    o.x = f2bf(v.x); o.y = f2bf(v.y); o.z = f2bf(v.z); o.w = f2bf(v.w);
    reinterpret_cast<ushort4*>(Xb)[i] = o;
    Xq[i] = enc4fp8(v.x, v.y, v.z, v.w);
}

// ------- phase A: bucket edges by coarse key, PACKED entries ----------------
__global__ __launch_bounds__(256) void bucket_scatter(
    const int* __restrict__ ei,
    int* __restrict__ gcurF, int* __restrict__ gcurB,
    int* __restrict__ bktF, int* __restrict__ bktB,
    int e, int nb) {
    extern __shared__ int lds[];             // cntF[nb], cntB[nb]
    int* cntF = lds;
    int* cntB = lds + nb;
    int t = threadIdx.x;
    for (int i = t; i < 2 * nb; i += 256) lds[i] = 0;
    __syncthreads();
    int base = blockIdx.x * 2048;
    int i0 = base + t * 8;
    int s[8], d[8], rf[8], rb[8];
    if (i0 + 8 <= e && (e & 3) == 0) {       // vector path (2x int4 per side)
        i32x4 sa = *reinterpret_cast<const i32x4*>(ei + i0);
        i32x4 sb = *reinterpret_cast<const i32x4*>(ei + i0 + 4);
        i32x4 da = *reinterpret_cast<const i32x4*>(ei + e + i0);
        i32x4 db = *reinterpret_cast<const i32x4*>(ei + e + i0 + 4);
        s[0]=sa.x; s[1]=sa.y; s[2]=sa.z; s[3]=sa.w;
        s[4]=sb.x; s[5]=sb.y; s[6]=sb.z; s[7]=sb.w;
        d[0]=da.x; d[1]=da.y; d[2]=da.z; d[3]=da.w;
        d[4]=db.x; d[5]=db.y; d[6]=db.z; d[7]=db.w;
    } else {
#pragma unroll
        for (int k = 0; k < 8; k++) {
            int idx = i0 + k;
            s[k] = (idx < e) ? ei[idx] : 0;
            d[k] = (idx < e) ? ei[e + idx] : 0;
        }
    }
#pragma unroll
    for (int k = 0; k < 8; k++) {
        if (i0 + k < e) {
            rf[k] = atomicAdd(&cntF[d[k] >> BSHIFT], 1);
            rb[k] = atomicAdd(&cntB[s[k] >> BSHIFT], 1);
        }
    }
    __syncthreads();
    for (int c = t; c < nb; c += 256) {
        int vF = cntF[c];
        if (vF) cntF[c] = atomicAdd(&gcurF[(size_t)c * PADI], vF);
        int vB = cntB[c];
        if (vB) cntB[c] = atomicAdd(&gcurB[(size_t)c * PADI], vB);
    }
    __syncthreads();
#pragma unroll
    for (int k = 0; k < 8; k++) {
        if (i0 + k < e) {
            int cF = d[k] >> BSHIFT;
            int slotF = cntF[cF] + rf[k];
            if (slotF < CAP) bktF[(size_t)cF * CAP + slotF] = (s[k] << 9) | (d[k] & BMASK);
            int cB = s[k] >> BSHIFT;
            int slotB = cntB[cB] + rb[k];
            if (slotB < CAP) bktB[(size_t)cB * CAP + slotB] = (d[k] << 9) | (s[k] & BMASK);
        }
    }
}

// ------- phase B: per-bucket CSR finalize, both dirs, inline base scan ------
// dir-0 blocks additionally histogram batch[] -> pcnt (pool node counts).
__global__ __launch_bounds__(256) void bucket_csr_all(
    const int* __restrict__ bktF, const int* __restrict__ bktB,
    const int* __restrict__ gcurF, const int* __restrict__ gcurB,
    int* __restrict__ csr_f, int* __restrict__ csr_b,
    int* __restrict__ off_f, int* __restrict__ off_b,
    float* __restrict__ invf, float* __restrict__ invb,
    const int* __restrict__ batch, float* __restrict__ pcnt,
    int n, int nb, int e) {
    const int dir = blockIdx.y;
    const int* bkt = dir ? bktB : bktF;
    const int* gcur = dir ? gcurB : gcurF;
    int* csr = dir ? csr_b : csr_f;
    int* off = dir ? off_b : off_f;
    float* inv = dir ? invb : invf;
    const int c = blockIdx.x;
    const int t = threadIdx.x;

    // ---- inline exclusive scan of bucket sizes (nb <= 256) -> gb ----
    __shared__ int sb[2][256];
    int v = (t < nb) ? min(gcur[(size_t)t * PADI], CAP) : 0;
    sb[0][t] = v;
    __syncthreads();
    int pq = 0;
    for (int ofs = 1; ofs < 256; ofs <<= 1) {
        int u = sb[pq][t];
        if (t >= ofs) u += sb[pq][t - ofs];
        sb[pq ^ 1][t] = u;
        __syncthreads();
        pq ^= 1;
    }
    int size = min(gcur[(size_t)c * PADI], CAP);
    int gb = sb[pq][c] - size;               // exclusive prefix at c
    if (t == 0 && c == 0) off[n] = e;

    // ---- pcnt histogram (dir 0 only): 512 nodes of this bucket ----
    __shared__ int hg[GG];
    if (dir == 0) {
        for (int l = t; l < GG; l += 256) hg[l] = 0;
        __syncthreads();
        for (int l = t; l < BNODES; l += 256) {
            int node = c * BNODES + l;
            if (node < n) atomicAdd(&hg[batch[node]], 1);
        }
        __syncthreads();
        for (int l = t; l < GG; l += 256)
            if (hg[l]) atomicAdd(&pcnt[l], (float)hg[l]);
    }

    // ---- per-bucket histogram + scan + place ----
    __shared__ int cnt[BNODES];
    __shared__ int cur[BNODES];
    __shared__ int sc[2][BNODES];
    const int* src = bkt + (size_t)c * CAP;
    for (int l = t; l < BNODES; l += 256) cnt[l] = 0;
    __syncthreads();
    for (int i = t; i < size; i += 256)
        atomicAdd(&cnt[src[i] & BMASK], 1);
    __syncthreads();
    for (int l = t; l < BNODES; l += 256) sc[0][l] = cnt[l];
    __syncthreads();
    int pp = 0;
    for (int ofs = 1; ofs < BNODES; ofs <<= 1) {
        for (int l = t; l < BNODES; l += 256) {
            int u = sc[pp][l];
            if (l >= ofs) u += sc[pp][l - ofs];
            sc[pp ^ 1][l] = u;
        }
        __syncthreads();
        pp ^= 1;
    }
    for (int l = t; l < BNODES; l += 256) {
        int excl = sc[pp][l] - cnt[l];
        cur[l] = excl;
        int node = c * BNODES + l;
        if (node < n) {
            off[node] = gb + excl;
            inv[node] = 1.f / fmaxf((float)cnt[l], 1.f);
        }
    }
    __syncthreads();
    for (int i = t; i < size; i += 256) {
        int vk = src[i];
        int slot = atomicAdd(&cur[vk & BMASK], 1);
        csr[gb + slot] = vk >> 9;
    }
}

// ---- gather-mean: fp8 row reads (64B = 1 line/row), f32 acc, bf16 agg out --
__global__ __launch_bounds__(256) void gather_mean_q8(
    const unsigned char* __restrict__ Xq,
    const int* __restrict__ off_f, const int* __restrict__ csr_f,
    const float* __restrict__ invf,
    const int* __restrict__ off_b, const int* __restrict__ csr_b,
    const float* __restrict__ invb,
    ushort* __restrict__ aggf, ushort* __restrict__ aggb, int n) {
    int tid = blockIdx.x * 256 + threadIdx.x;
    int node = tid >> 5;
    if (node >= n) return;
    int dir = (tid >> 4) & 1;
    int c = (tid & 15) * 4;            // element offset (4 elems = 4 bytes fp8)
    const int* off = dir ? off_b : off_f;
    const int* csr = dir ? csr_b : csr_f;
    const float* inv = dir ? invb : invf;
    ushort* agg = dir ? aggb : aggf;

    int b = off[node], en = off[node + 1];
    float ax = 0.f, ay = 0.f, az = 0.f, aw = 0.f;
    int k = b;
    for (; k + 3 < en; k += 4) {
        int n0 = csr[k], n1 = csr[k + 1], n2 = csr[k + 2], n3 = csr[k + 3];
        unsigned u0 = *reinterpret_cast<const unsigned*>(Xq + (size_t)n0 * 64 + c);
        unsigned u1 = *reinterpret_cast<const unsigned*>(Xq + (size_t)n1 * 64 + c);
        unsigned u2 = *reinterpret_cast<const unsigned*>(Xq + (size_t)n2 * 64 + c);
        unsigned u3 = *reinterpret_cast<const unsigned*>(Xq + (size_t)n3 * 64 + c);
        f32x2 l0 = __builtin_amdgcn_cvt_pk_f32_fp8((int)u0, false);
        f32x2 h0 = __builtin_amdgcn_cvt_pk_f32_fp8((int)u0, true);
        f32x2 l1 = __builtin_amdgcn_cvt_pk_f32_fp8((int)u1, false);
        f32x2 h1 = __builtin_amdgcn_cvt_pk_f32_fp8((int)u1, true);
        f32x2 l2 = __builtin_amdgcn_cvt_pk_f32_fp8((int)u2, false);
        f32x2 h2 = __builtin_amdgcn_cvt_pk_f32_fp8((int)u2, true);
        f32x2 l3 = __builtin_amdgcn_cvt_pk_f32_fp8((int)u3, false);
        f32x2 h3 = __builtin_amdgcn_cvt_pk_f32_fp8((int)u3, true);
        ax += l0.x + l1.x + l2.x + l3.x;
        ay += l0.y + l1.y + l2.y + l3.y;
        az += h0.x + h1.x + h2.x + h3.x;
        aw += h0.y + h1.y + h2.y + h3.y;
    }
    for (; k < en; k++) {
        int s = csr[k];
        unsigned u = *reinterpret_cast<const unsigned*>(Xq + (size_t)s * 64 + c);
        f32x2 lo = __builtin_amdgcn_cvt_pk_f32_fp8((int)u, false);
        f32x2 hi = __builtin_amdgcn_cvt_pk_f32_fp8((int)u, true);
        ax += lo.x; ay += lo.y; az += hi.x; aw += hi.y;
    }
    float iv = inv[node];
    ushort4 r;
    r.x = f2bf(ax * iv); r.y = f2bf(ay * iv); r.z = f2bf(az * iv); r.w = f2bf(aw * iv);
    *reinterpret_cast<ushort4*>(agg + (size_t)node * 64 + c) = r;
}

// ---------------- fused bidirectional SAGE layer (MFMA bf16) ----------------
// out = relu(0.5*(aggf@Wlf^T + aggb@Wlb^T + xb@(Wrf+Wrb)^T) + 0.5*(blf+blb))
// Layer 0 (psum==nullptr): writes bf16 OutB + fp8 OutQ.
// Layer 1 (psum!=nullptr): NO global h-writes; pools directly into psum via
// LDS (nodes are consecutive & batch sorted -> block spans ~1-2 graphs).
__global__ __launch_bounds__(256) void fused_sage_mfma(
    const ushort* __restrict__ Xb,
    const ushort* __restrict__ aggf, const ushort* __restrict__ aggb,
    const float* __restrict__ Wlf, const float* __restrict__ blf,
    const float* __restrict__ Wrf,
    const float* __restrict__ Wlb, const float* __restrict__ blb,
    const float* __restrict__ Wrb,
    ushort* __restrict__ OutB, unsigned char* __restrict__ OutQ,
    float* __restrict__ psum, const int* __restrict__ batch, int n)
{
    // LDS arena: [0,9216) sA (64x72 ushort); [9216,36864) sW (3x64x72 ushort);
    // [36864,37120) bias. Pool phase reuses [0,32768) as float ls[GG*64] slice.
    __shared__ __align__(16) char arena[37120];
    ushort* sA_ = reinterpret_cast<ushort*>(arena);                 // [row*72+c]
    ushort* sW_ = reinterpret_cast<ushort*>(arena + 9216);          // [(p*64+row)*72+c]
    float*  sBias = reinterpret_cast<float*>(arena + 36864);
    const int t = threadIdx.x;
    const int base = blockIdx.x * 64;
    const int lane = t & 63;
    const int m0 = (t >> 6) * 16;       // wave's row offset
    const int lr = lane & 15;           // A row / B col / D col
    const int kb = lane >> 4;           // k-block 0..3

    // ---- stage weights (bf16) + bias, once ----
#pragma unroll
    for (int i = 0; i < 4; i++) {
        int idx4 = t + 256 * i;               // 1024 float4s = 64x64
        int row = idx4 >> 4, c4 = idx4 & 15;
        float4 w0 = *reinterpret_cast<const float4*>(Wlf + row * 64 + c4 * 4);
        float4 w1 = *reinterpret_cast<const float4*>(Wlb + row * 64 + c4 * 4);
        float4 wa = *reinterpret_cast<const float4*>(Wrf + row * 64 + c4 * 4);
        float4 wb = *reinterpret_cast<const float4*>(Wrb + row * 64 + c4 * 4);
        ushort4 o;
        o.x = f2bf(w0.x); o.y = f2bf(w0.y); o.z = f2bf(w0.z); o.w = f2bf(w0.w);
        *reinterpret_cast<ushort4*>(&sW_[(0 * 64 + row) * 72 + c4 * 4]) = o;
        o.x = f2bf(w1.x); o.y = f2bf(w1.y); o.z = f2bf(w1.z); o.w = f2bf(w1.w);
        *reinterpret_cast<ushort4*>(&sW_[(1 * 64 + row) * 72 + c4 * 4]) = o;
        o.x = f2bf(wa.x + wb.x); o.y = f2bf(wa.y + wb.y);
        o.z = f2bf(wa.z + wb.z); o.w = f2bf(wa.w + wb.w);
        *reinterpret_cast<ushort4*>(&sW_[(2 * 64 + row) * 72 + c4 * 4]) = o;
    }
    if (t < 64) sBias[t] = 0.5f * (blf[t] + blb[t]);

    f32x4 acc0 = {0.f, 0.f, 0.f, 0.f};
    f32x4 acc1 = {0.f, 0.f, 0.f, 0.f};
    f32x4 acc2 = {0.f, 0.f, 0.f, 0.f};
    f32x4 acc3 = {0.f, 0.f, 0.f, 0.f};

    for (int p = 0; p < 3; p++) {
        const ushort* src = (p == 0) ? aggf : (p == 1) ? aggb : Xb;
        __syncthreads();
        // ---- stage A tile: 64 rows x 64 bf16, 16B per thread x2 ----
#pragma unroll
        for (int i = 0; i < 2; i++) {
            int c8 = t + 256 * i;             // 512 chunks of 8 bf16
            int row = c8 >> 3, k8 = (c8 & 7) * 8;
            int node = base + row;
            uint4 v = make_uint4(0u, 0u, 0u, 0u);
            if (node < n)
                v = *reinterpret_cast<const uint4*>(src + (size_t)node * 64 + k8);
            *reinterpret_cast<uint4*>(&sA_[row * 72 + k8]) = v;
        }
        __syncthreads();
        // ---- MFMA: 2 k-halves x 4 col-blocks ----
#pragma unroll
        for (int kh = 0; kh < 2; kh++) {
            bf16x8 a = *(const bf16x8*)(&sA_[(m0 + lr) * 72 + kh * 32 + kb * 8]);
            bf16x8 b0 = *(const bf16x8*)(&sW_[(p * 64 + 0 * 16 + lr) * 72 + kh * 32 + kb * 8]);
            bf16x8 b1 = *(const bf16x8*)(&sW_[(p * 64 + 1 * 16 + lr) * 72 + kh * 32 + kb * 8]);
            bf16x8 b2 = *(const bf16x8*)(&sW_[(p * 64 + 2 * 16 + lr) * 72 + kh * 32 + kb * 8]);
            bf16x8 b3 = *(const bf16x8*)(&sW_[(p * 64 + 3 * 16 + lr) * 72 + kh * 32 + kb * 8]);
            acc0 = __builtin_amdgcn_mfma_f32_16x16x32_bf16(a, b0, acc0, 0, 0, 0);
            acc1 = __builtin_amdgcn_mfma_f32_16x16x32_bf16(a, b1, acc1, 0, 0, 0);
            acc2 = __builtin_amdgcn_mfma_f32_16x16x32_bf16(a, b2, acc2, 0, 0, 0);
            acc3 = __builtin_amdgcn_mfma_f32_16x16x32_bf16(a, b3, acc3, 0, 0, 0);
        }
    }
    __syncthreads();   // all waves done with sA/sW before arena reuse

    if (psum) {
        // ---- layer 1: fused global mean-pool (no h1 stores) ----
        float* ls = reinterpret_cast<float*>(arena);     // [GG*64] slice
        int lastrow = base + 63 < n - 1 ? base + 63 : n - 1;
        int gmin = batch[base];
        int gmax = batch[lastrow];
        int span = (gmax - gmin + 1) * 64;
        for (int i = t; i < span; i += 256) ls[gmin * 64 + i] = 0.f;
        __syncthreads();
#pragma unroll
        for (int b = 0; b < 4; b++) {
            int j = lr + 16 * b;
            float bias = sBias[j];
            f32x4 ac = (b == 0) ? acc0 : (b == 1) ? acc1 : (b == 2) ? acc2 : acc3;
#pragma unroll
            for (int i = 0; i < 4; i++) {
                int row = base + m0 + kb * 4 + i;
                if (row < n) {
                    float v = 0.5f * ac[i] + bias;
                    v = v > 0.f ? v : 0.f;
                    atomicAdd(&ls[batch[row] * 64 + j], v);
                }
            }
        }
        __syncthreads();
        for (int i = t; i < span; i += 256) {
            float vv = ls[gmin * 64 + i];
            if (vv != 0.f) atomicAdd(&psum[gmin * 64 + i], vv);
        }
    } else {
        // ---- layer 0: bias + relu; bf16 stores + fp8 via LDS repack ----
        unsigned char* sQ = reinterpret_cast<unsigned char*>(arena); // [64][80]
#pragma unroll
        for (int b = 0; b < 4; b++) {
            int j = lr + 16 * b;
            float bias = sBias[j];
            f32x4 ac = (b == 0) ? acc0 : (b == 1) ? acc1 : (b == 2) ? acc2 : acc3;
#pragma unroll
            for (int i = 0; i < 4; i++) {
                int row = m0 + kb * 4 + i;
                float v = 0.5f * ac[i] + bias;
                v = v > 0.f ? v : 0.f;
                if (base + row < n) OutB[(size_t)(base + row) * 64 + j] = f2bf(v);
                sQ[row * 80 + j] = enc1fp8(v);
            }
        }
        __syncthreads();
        int row = t >> 2, c16 = (t & 3) * 16;
        if (base + row < n) {
            uint4 v = *reinterpret_cast<const uint4*>(&sQ[row * 80 + c16]);
            *reinterpret_cast<uint4*>(OutQ + (size_t)(base + row) * 64 + c16) = v;
        }
    }
}

// ---------------- head ----------------
__global__ __launch_bounds__(256) void pool_final(const float* __restrict__ psum,
                                                  const float* __restrict__ pcnt,
                                                  const float* __restrict__ PW,
                                                  const float* __restrict__ Pb,
                                                  float* __restrict__ out) {
    int t = blockIdx.x * 256 + threadIdx.x;
    int g = t >> 4, o = t & 15;
    if (g >= GG) return;
    float inv = 1.f / fmaxf(pcnt[g], 1.f);
    float acc = 0.f;
#pragma unroll 8
    for (int k = 0; k < 64; k++) acc += psum[g * 64 + k] * PW[o * 64 + k];
    out[t] = acc * inv + Pb[o];
}

extern "C" void kernel_launch(void* const* d_in, const int* in_sizes, int n_in,
                              void* d_out, int out_size, void* d_ws, size_t ws_size,
                              hipStream_t stream) {
    const float* x      = (const float*)d_in[0];
    const int*   ei     = (const int*)d_in[1];
    const int*   batch  = (const int*)d_in[2];
    const float* l0f_Wl = (const float*)d_in[4];
    const float* l0f_bl = (const float*)d_in[5];
    const float* l0f_Wr = (const float*)d_in[6];
    const float* l0b_Wl = (const float*)d_in[7];
    const float* l0b_bl = (const float*)d_in[8];
    const float* l0b_Wr = (const float*)d_in[9];
    const float* l1f_Wl = (const float*)d_in[10];
    const float* l1f_bl = (const float*)d_in[11];
    const float* l1f_Wr = (const float*)d_in[12];
    const float* l1b_Wl = (const float*)d_in[13];
    const float* l1b_bl = (const float*)d_in[14];
    const float* l1b_Wr = (const float*)d_in[15];
    const float* pred_W = (const float*)d_in[16];
    const float* pred_b = (const float*)d_in[17];

    const int n = in_sizes[0] / 64;
    const int e = in_sizes[1] / 2;
    const int nb = (n + BNODES - 1) >> BSHIFT;   // <= 256 required

    // ---- workspace layout (int elements) ----
    int* ws = (int*)d_ws;
    size_t o = 0;
    int*   gcurF = ws + o;  o += (size_t)nb * PADI;      // zeroed
    int*   gcurB = ws + o;  o += (size_t)nb * PADI;      // zeroed
    float* psum  = (float*)(ws + o); o += GG * 64;       // zeroed
    float* pcnt  = (float*)(ws + o); o += GG;            // zeroed
    size_t zcount = o;
    int*   off_f = ws + o;  o += n + 1;
    int*   off_b = ws + o;  o += n + 1;
    float* invf  = (float*)(ws + o); o += n;
    float* invb  = (float*)(ws + o); o += n;
    int*   csr_f = ws + o;  o += e;
    int*   csr_b = ws + o;  o += e;
    o = (o + 15) & ~(size_t)15;                          // 64B align
    int*   bktF  = ws + o;  o += (size_t)nb * CAP;       // packed entries
    int*   bktB  = ws + o;  o += (size_t)nb * CAP;
    ushort* xb    = (ushort*)(ws + o); o += (size_t)n * 32;  // [n][64] bf16 (x->h0)
    ushort* aggfb = (ushort*)(ws + o); o += (size_t)n * 32;  // [n][64] bf16
    ushort* aggbb = (ushort*)(ws + o); o += (size_t)n * 32;  // [n][64] bf16
    o = (o + 15) & ~(size_t)15;                          // 64B align for fp8 rows
    unsigned* xq  = (unsigned*)(ws + o); o += (size_t)n * 16; // [n][64] fp8 (x->h0)

    // ---- prep (zero + convert), then CSR build via bucket counting-sort ----
    prep<<<(n * 16 + 255) / 256, 256, 0, stream>>>(x, xb, xq, n * 16, ws, (int)zcount);
    bucket_scatter<<<(e + 2047) / 2048, 256, 2 * nb * sizeof(int), stream>>>(
        ei, gcurF, gcurB, bktF, bktB, e, nb);
    bucket_csr_all<<<dim3(nb, 2), 256, 0, stream>>>(
        bktF, bktB, gcurF, gcurB, csr_f, csr_b, off_f, off_b, invf, invb,
        batch, pcnt, n, nb, e);

    // layer 0: fp8 gather -> bf16 agg; MFMA sage -> h0 (bf16 xb + fp8 xq)
    gather_mean_q8<<<((size_t)n * 32 + 255) / 256, 256, 0, stream>>>(
        (const unsigned char*)xq, off_f, csr_f, invf, off_b, csr_b, invb,
        aggfb, aggbb, n);
    fused_sage_mfma<<<(n + 63) / 64, 256, 0, stream>>>(xb, aggfb, aggbb,
        l0f_Wl, l0f_bl, l0f_Wr, l0b_Wl, l0b_bl, l0b_Wr,
        xb, (unsigned char*)xq, (float*)nullptr, (const int*)nullptr, n);

    // layer 1: fp8 gather -> bf16 agg; MFMA sage pools directly into psum
    gather_mean_q8<<<((size_t)n * 32 + 255) / 256, 256, 0, stream>>>(
        (const unsigned char*)xq, off_f, csr_f, invf, off_b, csr_b, invb,
        aggfb, aggbb, n);
    fused_sage_mfma<<<(n + 63) / 64, 256, 0, stream>>>(xb, aggfb, aggbb,
        l1f_Wl, l1f_bl, l1f_Wr, l1b_Wl, l1b_bl, l1b_Wr,
        (ushort*)nullptr, (unsigned char*)nullptr, psum, batch, n);

    // head
    pool_final<<<8, 256, 0, stream>>>(psum, pcnt, pred_W, pred_b, (float*)d_out);
}

// Round 18
// 181.933 us; speedup vs baseline: 2.0374x; 1.1393x over previous
//
#include <hip/hip_runtime.h>
#include <hip/hip_bf16.h>

#define GG 128      // num_graphs (static in problem)
#define BSHIFT 9    // 512 nodes per bucket
#define BMASK 511
#define BNODES 512
#define PADI 16     // ints per padded global bucket counter (one 64B line each)
#define CAP 8192    // bucket capacity (mean ~5100 at n=100k,e=1M)

typedef __attribute__((ext_vector_type(8))) short bf16x8;
typedef __attribute__((ext_vector_type(4))) float f32x4;
typedef __attribute__((ext_vector_type(2))) float f32x2;
typedef __attribute__((ext_vector_type(4))) int i32x4;

// ---------------- bf16 helpers (RNE) ----------------
__device__ __forceinline__ ushort f2bf(float f) {
    union { float f; unsigned u; } v; v.f = f;
    unsigned r = v.u + 0x7FFF + ((v.u >> 16) & 1);
    return (ushort)(r >> 16);
}
__device__ __forceinline__ float bf2f(ushort s) {
    union { unsigned u; float f; } v; v.u = ((unsigned)s) << 16;
    return v.f;
}

// ---------------- fp8 helpers (native gfx950 converters) ----------------
__device__ __forceinline__ unsigned enc4fp8(float v0, float v1, float v2, float v3) {
    int p = __builtin_amdgcn_cvt_pk_fp8_f32(v0, v1, 0, false);
    p = __builtin_amdgcn_cvt_pk_fp8_f32(v2, v3, p, true);
    return (unsigned)p;
}
__device__ __forceinline__ unsigned char enc1fp8(float v) {
    return (unsigned char)(__builtin_amdgcn_cvt_pk_fp8_f32(v, v, 0, false) & 0xFF);
}

// ------- prep: zero counters + f32 -> bf16 + fp8 rows (fused) ---------------
__global__ __launch_bounds__(256) void prep(const float* __restrict__ X,
                                            ushort* __restrict__ Xb,
                                            unsigned* __restrict__ Xq,
                                            int n4, int* __restrict__ z, int zc) {
    int i = blockIdx.x * 256 + threadIdx.x;
    if (i < zc) z[i] = 0;
    if (i >= n4) return;
    float4 v = reinterpret_cast<const float4*>(X)[i];
    ushort4 o;
    o.x = f2bf(v.x); o.y = f2bf(v.y); o.z = f2bf(v.z); o.w = f2bf(v.w);
    reinterpret_cast<ushort4*>(Xb)[i] = o;
    Xq[i] = enc4fp8(v.x, v.y, v.z, v.w);
}

// ------- phase A: bucket edges by coarse key, PACKED entries ----------------
__global__ __launch_bounds__(256) void bucket_scatter(
    const int* __restrict__ ei,
    int* __restrict__ gcurF, int* __restrict__ gcurB,
    int* __restrict__ bktF, int* __restrict__ bktB,
    int e, int nb) {
    extern __shared__ int lds[];             // cntF[nb], cntB[nb]
    int* cntF = lds;
    int* cntB = lds + nb;
    int t = threadIdx.x;
    for (int i = t; i < 2 * nb; i += 256) lds[i] = 0;
    __syncthreads();
    int base = blockIdx.x * 2048;
    int i0 = base + t * 8;
    int s[8], d[8], rf[8], rb[8];
    if (i0 + 8 <= e && (e & 3) == 0) {       // vector path (2x int4 per side)
        i32x4 sa = *reinterpret_cast<const i32x4*>(ei + i0);
        i32x4 sb = *reinterpret_cast<const i32x4*>(ei + i0 + 4);
        i32x4 da = *reinterpret_cast<const i32x4*>(ei + e + i0);
        i32x4 db = *reinterpret_cast<const i32x4*>(ei + e + i0 + 4);
        s[0]=sa.x; s[1]=sa.y; s[2]=sa.z; s[3]=sa.w;
        s[4]=sb.x; s[5]=sb.y; s[6]=sb.z; s[7]=sb.w;
        d[0]=da.x; d[1]=da.y; d[2]=da.z; d[3]=da.w;
        d[4]=db.x; d[5]=db.y; d[6]=db.z; d[7]=db.w;
    } else {
#pragma unroll
        for (int k = 0; k < 8; k++) {
            int idx = i0 + k;
            s[k] = (idx < e) ? ei[idx] : 0;
            d[k] = (idx < e) ? ei[e + idx] : 0;
        }
    }
#pragma unroll
    for (int k = 0; k < 8; k++) {
        if (i0 + k < e) {
            rf[k] = atomicAdd(&cntF[d[k] >> BSHIFT], 1);
            rb[k] = atomicAdd(&cntB[s[k] >> BSHIFT], 1);
        }
    }
    __syncthreads();
    for (int c = t; c < nb; c += 256) {
        int vF = cntF[c];
        if (vF) cntF[c] = atomicAdd(&gcurF[(size_t)c * PADI], vF);
        int vB = cntB[c];
        if (vB) cntB[c] = atomicAdd(&gcurB[(size_t)c * PADI], vB);
    }
    __syncthreads();
#pragma unroll
    for (int k = 0; k < 8; k++) {
        if (i0 + k < e) {
            int cF = d[k] >> BSHIFT;
            int slotF = cntF[cF] + rf[k];
            if (slotF < CAP) bktF[(size_t)cF * CAP + slotF] = (s[k] << 9) | (d[k] & BMASK);
            int cB = s[k] >> BSHIFT;
            int slotB = cntB[cB] + rb[k];
            if (slotB < CAP) bktB[(size_t)cB * CAP + slotB] = (d[k] << 9) | (s[k] & BMASK);
        }
    }
}

// ------- phase B: per-bucket CSR finalize, both dirs, inline base scan ------
// dir-0 blocks additionally histogram batch[] -> pcnt (pool node counts).
__global__ __launch_bounds__(256) void bucket_csr_all(
    const int* __restrict__ bktF, const int* __restrict__ bktB,
    const int* __restrict__ gcurF, const int* __restrict__ gcurB,
    int* __restrict__ csr_f, int* __restrict__ csr_b,
    int* __restrict__ off_f, int* __restrict__ off_b,
    float* __restrict__ invf, float* __restrict__ invb,
    const int* __restrict__ batch, float* __restrict__ pcnt,
    int n, int nb, int e) {
    const int dir = blockIdx.y;
    const int* bkt = dir ? bktB : bktF;
    const int* gcur = dir ? gcurB : gcurF;
    int* csr = dir ? csr_b : csr_f;
    int* off = dir ? off_b : off_f;
    float* inv = dir ? invb : invf;
    const int c = blockIdx.x;
    const int t = threadIdx.x;

    // ---- inline exclusive scan of bucket sizes (nb <= 256) -> gb ----
    __shared__ int sb[2][256];
    int v = (t < nb) ? min(gcur[(size_t)t * PADI], CAP) : 0;
    sb[0][t] = v;
    __syncthreads();
    int pq = 0;
    for (int ofs = 1; ofs < 256; ofs <<= 1) {
        int u = sb[pq][t];
        if (t >= ofs) u += sb[pq][t - ofs];
        sb[pq ^ 1][t] = u;
        __syncthreads();
        pq ^= 1;
    }
    int size = min(gcur[(size_t)c * PADI], CAP);
    int gb = sb[pq][c] - size;               // exclusive prefix at c
    if (t == 0 && c == 0) off[n] = e;

    // ---- pcnt histogram (dir 0 only): 512 nodes of this bucket ----
    __shared__ int hg[GG];
    if (dir == 0) {
        for (int l = t; l < GG; l += 256) hg[l] = 0;
        __syncthreads();
        for (int l = t; l < BNODES; l += 256) {
            int node = c * BNODES + l;
            if (node < n) atomicAdd(&hg[batch[node]], 1);
        }
        __syncthreads();
        for (int l = t; l < GG; l += 256)
            if (hg[l]) atomicAdd(&pcnt[l], (float)hg[l]);
    }

    // ---- per-bucket histogram + scan + place ----
    __shared__ int cnt[BNODES];
    __shared__ int cur[BNODES];
    __shared__ int sc[2][BNODES];
    const int* src = bkt + (size_t)c * CAP;
    for (int l = t; l < BNODES; l += 256) cnt[l] = 0;
    __syncthreads();
    for (int i = t; i < size; i += 256)
        atomicAdd(&cnt[src[i] & BMASK], 1);
    __syncthreads();
    for (int l = t; l < BNODES; l += 256) sc[0][l] = cnt[l];
    __syncthreads();
    int pp = 0;
    for (int ofs = 1; ofs < BNODES; ofs <<= 1) {
        for (int l = t; l < BNODES; l += 256) {
            int u = sc[pp][l];
            if (l >= ofs) u += sc[pp][l - ofs];
            sc[pp ^ 1][l] = u;
        }
        __syncthreads();
        pp ^= 1;
    }
    for (int l = t; l < BNODES; l += 256) {
        int excl = sc[pp][l] - cnt[l];
        cur[l] = excl;
        int node = c * BNODES + l;
        if (node < n) {
            off[node] = gb + excl;
            inv[node] = 1.f / fmaxf((float)cnt[l], 1.f);
        }
    }
    __syncthreads();
    for (int i = t; i < size; i += 256) {
        int vk = src[i];
        int slot = atomicAdd(&cur[vk & BMASK], 1);
        csr[gb + slot] = vk >> 9;
    }
}

// ---- gather-mean: fp8 row reads (64B = 1 line/row), f32 acc, bf16 agg out --
__global__ __launch_bounds__(256) void gather_mean_q8(
    const unsigned char* __restrict__ Xq,
    const int* __restrict__ off_f, const int* __restrict__ csr_f,
    const float* __restrict__ invf,
    const int* __restrict__ off_b, const int* __restrict__ csr_b,
    const float* __restrict__ invb,
    ushort* __restrict__ aggf, ushort* __restrict__ aggb, int n) {
    int tid = blockIdx.x * 256 + threadIdx.x;
    int node = tid >> 5;
    if (node >= n) return;
    int dir = (tid >> 4) & 1;
    int c = (tid & 15) * 4;            // element offset (4 elems = 4 bytes fp8)
    const int* off = dir ? off_b : off_f;
    const int* csr = dir ? csr_b : csr_f;
    const float* inv = dir ? invb : invf;
    ushort* agg = dir ? aggb : aggf;

    int b = off[node], en = off[node + 1];
    float ax = 0.f, ay = 0.f, az = 0.f, aw = 0.f;
    int k = b;
    for (; k + 3 < en; k += 4) {
        int n0 = csr[k], n1 = csr[k + 1], n2 = csr[k + 2], n3 = csr[k + 3];
        unsigned u0 = *reinterpret_cast<const unsigned*>(Xq + (size_t)n0 * 64 + c);
        unsigned u1 = *reinterpret_cast<const unsigned*>(Xq + (size_t)n1 * 64 + c);
        unsigned u2 = *reinterpret_cast<const unsigned*>(Xq + (size_t)n2 * 64 + c);
        unsigned u3 = *reinterpret_cast<const unsigned*>(Xq + (size_t)n3 * 64 + c);
        f32x2 l0 = __builtin_amdgcn_cvt_pk_f32_fp8((int)u0, false);
        f32x2 h0 = __builtin_amdgcn_cvt_pk_f32_fp8((int)u0, true);
        f32x2 l1 = __builtin_amdgcn_cvt_pk_f32_fp8((int)u1, false);
        f32x2 h1 = __builtin_amdgcn_cvt_pk_f32_fp8((int)u1, true);
        f32x2 l2 = __builtin_amdgcn_cvt_pk_f32_fp8((int)u2, false);
        f32x2 h2 = __builtin_amdgcn_cvt_pk_f32_fp8((int)u2, true);
        f32x2 l3 = __builtin_amdgcn_cvt_pk_f32_fp8((int)u3, false);
        f32x2 h3 = __builtin_amdgcn_cvt_pk_f32_fp8((int)u3, true);
        ax += l0.x + l1.x + l2.x + l3.x;
        ay += l0.y + l1.y + l2.y + l3.y;
        az += h0.x + h1.x + h2.x + h3.x;
        aw += h0.y + h1.y + h2.y + h3.y;
    }
    for (; k < en; k++) {
        int s = csr[k];
        unsigned u = *reinterpret_cast<const unsigned*>(Xq + (size_t)s * 64 + c);
        f32x2 lo = __builtin_amdgcn_cvt_pk_f32_fp8((int)u, false);
        f32x2 hi = __builtin_amdgcn_cvt_pk_f32_fp8((int)u, true);
        ax += lo.x; ay += lo.y; az += hi.x; aw += hi.y;
    }
    float iv = inv[node];
    ushort4 r;
    r.x = f2bf(ax * iv); r.y = f2bf(ay * iv); r.z = f2bf(az * iv); r.w = f2bf(aw * iv);
    *reinterpret_cast<ushort4*>(agg + (size_t)node * 64 + c) = r;
}

// ---------------- fused bidirectional SAGE layer (MFMA bf16) ----------------
// out = relu(0.5*(aggf@Wlf^T + aggb@Wlb^T + xb@(Wrf+Wrb)^T) + 0.5*(blf+blb))
// Layer 0 (psum==nullptr): writes bf16 OutB + fp8 OutQ.
// Layer 1 (psum!=nullptr): NO global h-writes; wave-shuffle pooling into psum
// (batch sorted -> a wave's 16-row band is almost always one graph).
__global__ __launch_bounds__(256) void fused_sage_mfma(
    const ushort* __restrict__ Xb,
    const ushort* __restrict__ aggf, const ushort* __restrict__ aggb,
    const float* __restrict__ Wlf, const float* __restrict__ blf,
    const float* __restrict__ Wrf,
    const float* __restrict__ Wlb, const float* __restrict__ blb,
    const float* __restrict__ Wrb,
    ushort* __restrict__ OutB, unsigned char* __restrict__ OutQ,
    float* __restrict__ psum, const int* __restrict__ batch, int n)
{
    __shared__ ushort sA[64][72];       // +8 bf16 pad; reused as fp8 byte buffer
    __shared__ ushort sW[3][64][72];    // bf16 weights, W[j][k] layout
    __shared__ float  sBias[64];
    const int t = threadIdx.x;
    const int base = blockIdx.x * 64;
    const int lane = t & 63;
    const int m0 = (t >> 6) * 16;       // wave's row offset
    const int lr = lane & 15;           // A row / B col / D col
    const int kb = lane >> 4;           // k-block 0..3

    // ---- stage weights (bf16) + bias, once ----
#pragma unroll
    for (int i = 0; i < 4; i++) {
        int idx4 = t + 256 * i;               // 1024 float4s = 64x64
        int row = idx4 >> 4, c4 = idx4 & 15;
        float4 w0 = *reinterpret_cast<const float4*>(Wlf + row * 64 + c4 * 4);
        float4 w1 = *reinterpret_cast<const float4*>(Wlb + row * 64 + c4 * 4);
        float4 wa = *reinterpret_cast<const float4*>(Wrf + row * 64 + c4 * 4);
        float4 wb = *reinterpret_cast<const float4*>(Wrb + row * 64 + c4 * 4);
        ushort4 o;
        o.x = f2bf(w0.x); o.y = f2bf(w0.y); o.z = f2bf(w0.z); o.w = f2bf(w0.w);
        *reinterpret_cast<ushort4*>(&sW[0][row][c4 * 4]) = o;
        o.x = f2bf(w1.x); o.y = f2bf(w1.y); o.z = f2bf(w1.z); o.w = f2bf(w1.w);
        *reinterpret_cast<ushort4*>(&sW[1][row][c4 * 4]) = o;
        o.x = f2bf(wa.x + wb.x); o.y = f2bf(wa.y + wb.y);
        o.z = f2bf(wa.z + wb.z); o.w = f2bf(wa.w + wb.w);
        *reinterpret_cast<ushort4*>(&sW[2][row][c4 * 4]) = o;
    }
    if (t < 64) sBias[t] = 0.5f * (blf[t] + blb[t]);

    f32x4 acc0 = {0.f, 0.f, 0.f, 0.f};
    f32x4 acc1 = {0.f, 0.f, 0.f, 0.f};
    f32x4 acc2 = {0.f, 0.f, 0.f, 0.f};
    f32x4 acc3 = {0.f, 0.f, 0.f, 0.f};

    for (int p = 0; p < 3; p++) {
        const ushort* src = (p == 0) ? aggf : (p == 1) ? aggb : Xb;
        __syncthreads();
        // ---- stage A tile: 64 rows x 64 bf16, 16B per thread x2 ----
#pragma unroll
        for (int i = 0; i < 2; i++) {
            int c8 = t + 256 * i;             // 512 chunks of 8 bf16
            int row = c8 >> 3, k8 = (c8 & 7) * 8;
            int node = base + row;
            uint4 v = make_uint4(0u, 0u, 0u, 0u);
            if (node < n)
                v = *reinterpret_cast<const uint4*>(src + (size_t)node * 64 + k8);
            *reinterpret_cast<uint4*>(&sA[row][k8]) = v;
        }
        __syncthreads();
        // ---- MFMA: 2 k-halves x 4 col-blocks ----
#pragma unroll
        for (int kh = 0; kh < 2; kh++) {
            bf16x8 a = *(const bf16x8*)(&sA[m0 + lr][kh * 32 + kb * 8]);
            bf16x8 b0 = *(const bf16x8*)(&sW[p][0 * 16 + lr][kh * 32 + kb * 8]);
            bf16x8 b1 = *(const bf16x8*)(&sW[p][1 * 16 + lr][kh * 32 + kb * 8]);
            bf16x8 b2 = *(const bf16x8*)(&sW[p][2 * 16 + lr][kh * 32 + kb * 8]);
            bf16x8 b3 = *(const bf16x8*)(&sW[p][3 * 16 + lr][kh * 32 + kb * 8]);
            acc0 = __builtin_amdgcn_mfma_f32_16x16x32_bf16(a, b0, acc0, 0, 0, 0);
            acc1 = __builtin_amdgcn_mfma_f32_16x16x32_bf16(a, b1, acc1, 0, 0, 0);
            acc2 = __builtin_amdgcn_mfma_f32_16x16x32_bf16(a, b2, acc2, 0, 0, 0);
            acc3 = __builtin_amdgcn_mfma_f32_16x16x32_bf16(a, b3, acc3, 0, 0, 0);
        }
    }

    if (psum) {
        // ---- layer 1: wave-shuffle pooling (no h1 stores, no LDS reuse) ----
        int rlo = base + m0;
        int rhi = rlo + 15 < n - 1 ? rlo + 15 : n - 1;
        int g0 = batch[rlo < n - 1 ? rlo : n - 1];
        bool uniform = (g0 == batch[rhi]);
#pragma unroll
        for (int b = 0; b < 4; b++) {
            int j = lr + 16 * b;
            float bias = sBias[j];
            f32x4 ac = (b == 0) ? acc0 : (b == 1) ? acc1 : (b == 2) ? acc2 : acc3;
            if (uniform) {
                float s = 0.f;
#pragma unroll
                for (int i = 0; i < 4; i++) {
                    int row = base + m0 + kb * 4 + i;
                    if (row < n) {
                        float v = 0.5f * ac[i] + bias;
                        s += v > 0.f ? v : 0.f;
                    }
                }
                s += __shfl_xor(s, 16, 64);
                s += __shfl_xor(s, 32, 64);
                if (kb == 0) atomicAdd(&psum[g0 * 64 + j], s);
            } else {
#pragma unroll
                for (int i = 0; i < 4; i++) {
                    int row = base + m0 + kb * 4 + i;
                    if (row < n) {
                        float v = 0.5f * ac[i] + bias;
                        v = v > 0.f ? v : 0.f;
                        atomicAdd(&psum[batch[row] * 64 + j], v);
                    }
                }
            }
        }
    } else {
        // ---- layer 0: bias + relu; bf16 stores + fp8 via LDS repack ----
        __syncthreads();   // all waves done reading sA before repurposing
        unsigned char* sQ = reinterpret_cast<unsigned char*>(&sA[0][0]);  // [64][80]
#pragma unroll
        for (int b = 0; b < 4; b++) {
            int j = lr + 16 * b;
            float bias = sBias[j];
            f32x4 ac = (b == 0) ? acc0 : (b == 1) ? acc1 : (b == 2) ? acc2 : acc3;
#pragma unroll
            for (int i = 0; i < 4; i++) {
                int row = m0 + kb * 4 + i;
                float v = 0.5f * ac[i] + bias;
                v = v > 0.f ? v : 0.f;
                if (base + row < n) OutB[(size_t)(base + row) * 64 + j] = f2bf(v);
                sQ[row * 80 + j] = enc1fp8(v);
            }
        }
        __syncthreads();
        int row = t >> 2, c16 = (t & 3) * 16;
        if (base + row < n) {
            uint4 v = *reinterpret_cast<const uint4*>(&sQ[row * 80 + c16]);
            *reinterpret_cast<uint4*>(OutQ + (size_t)(base + row) * 64 + c16) = v;
        }
    }
}

// ---------------- head ----------------
__global__ __launch_bounds__(256) void pool_final(const float* __restrict__ psum,
                                                  const float* __restrict__ pcnt,
                                                  const float* __restrict__ PW,
                                                  const float* __restrict__ Pb,
                                                  float* __restrict__ out) {
    int t = blockIdx.x * 256 + threadIdx.x;
    int g = t >> 4, o = t & 15;
    if (g >= GG) return;
    float inv = 1.f / fmaxf(pcnt[g], 1.f);
    float acc = 0.f;
#pragma unroll 8
    for (int k = 0; k < 64; k++) acc += psum[g * 64 + k] * PW[o * 64 + k];
    out[t] = acc * inv + Pb[o];
}

extern "C" void kernel_launch(void* const* d_in, const int* in_sizes, int n_in,
                              void* d_out, int out_size, void* d_ws, size_t ws_size,
                              hipStream_t stream) {
    const float* x      = (const float*)d_in[0];
    const int*   ei     = (const int*)d_in[1];
    const int*   batch  = (const int*)d_in[2];
    const float* l0f_Wl = (const float*)d_in[4];
    const float* l0f_bl = (const float*)d_in[5];
    const float* l0f_Wr = (const float*)d_in[6];
    const float* l0b_Wl = (const float*)d_in[7];
    const float* l0b_bl = (const float*)d_in[8];
    const float* l0b_Wr = (const float*)d_in[9];
    const float* l1f_Wl = (const float*)d_in[10];
    const float* l1f_bl = (const float*)d_in[11];
    const float* l1f_Wr = (const float*)d_in[12];
    const float* l1b_Wl = (const float*)d_in[13];
    const float* l1b_bl = (const float*)d_in[14];
    const float* l1b_Wr = (const float*)d_in[15];
    const float* pred_W = (const float*)d_in[16];
    const float* pred_b = (const float*)d_in[17];

    const int n = in_sizes[0] / 64;
    const int e = in_sizes[1] / 2;
    const int nb = (n + BNODES - 1) >> BSHIFT;   // <= 256 required

    // ---- workspace layout (int elements) ----
    int* ws = (int*)d_ws;
    size_t o = 0;
    int*   gcurF = ws + o;  o += (size_t)nb * PADI;      // zeroed
    int*   gcurB = ws + o;  o += (size_t)nb * PADI;      // zeroed
    float* psum  = (float*)(ws + o); o += GG * 64;       // zeroed
    float* pcnt  = (float*)(ws + o); o += GG;            // zeroed
    size_t zcount = o;
    int*   off_f = ws + o;  o += n + 1;
    int*   off_b = ws + o;  o += n + 1;
    float* invf  = (float*)(ws + o); o += n;
    float* invb  = (float*)(ws + o); o += n;
    int*   csr_f = ws + o;  o += e;
    int*   csr_b = ws + o;  o += e;
    o = (o + 15) & ~(size_t)15;                          // 64B align
    int*   bktF  = ws + o;  o += (size_t)nb * CAP;       // packed entries
    int*   bktB  = ws + o;  o += (size_t)nb * CAP;
    ushort* xb    = (ushort*)(ws + o); o += (size_t)n * 32;  // [n][64] bf16 (x->h0)
    ushort* aggfb = (ushort*)(ws + o); o += (size_t)n * 32;  // [n][64] bf16
    ushort* aggbb = (ushort*)(ws + o); o += (size_t)n * 32;  // [n][64] bf16
    o = (o + 15) & ~(size_t)15;                          // 64B align for fp8 rows
    unsigned* xq  = (unsigned*)(ws + o); o += (size_t)n * 16; // [n][64] fp8 (x->h0)

    // ---- prep (zero + convert), then CSR build via bucket counting-sort ----
    prep<<<(n * 16 + 255) / 256, 256, 0, stream>>>(x, xb, xq, n * 16, ws, (int)zcount);
    bucket_scatter<<<(e + 2047) / 2048, 256, 2 * nb * sizeof(int), stream>>>(
        ei, gcurF, gcurB, bktF, bktB, e, nb);
    bucket_csr_all<<<dim3(nb, 2), 256, 0, stream>>>(
        bktF, bktB, gcurF, gcurB, csr_f, csr_b, off_f, off_b, invf, invb,
        batch, pcnt, n, nb, e);

    // layer 0: fp8 gather -> bf16 agg; MFMA sage -> h0 (bf16 xb + fp8 xq)
    gather_mean_q8<<<((size_t)n * 32 + 255) / 256, 256, 0, stream>>>(
        (const unsigned char*)xq, off_f, csr_f, invf, off_b, csr_b, invb,
        aggfb, aggbb, n);
    fused_sage_mfma<<<(n + 63) / 64, 256, 0, stream>>>(xb, aggfb, aggbb,
        l0f_Wl, l0f_bl, l0f_Wr, l0b_Wl, l0b_bl, l0b_Wr,
        xb, (unsigned char*)xq, (float*)nullptr, (const int*)nullptr, n);

    // layer 1: fp8 gather -> bf16 agg; MFMA sage pools into psum via shuffles
    gather_mean_q8<<<((size_t)n * 32 + 255) / 256, 256, 0, stream>>>(
        (const unsigned char*)xq, off_f, csr_f, invf, off_b, csr_b, invb,
        aggfb, aggbb, n);
    fused_sage_mfma<<<(n + 63) / 64, 256, 0, stream>>>(xb, aggfb, aggbb,
        l1f_Wl, l1f_bl, l1f_Wr, l1b_Wl, l1b_bl, l1b_Wr,
        (ushort*)nullptr, (unsigned char*)nullptr, psum, batch, n);

    // head
    pool_final<<<8, 256, 0, stream>>>(psum, pcnt, pred_W, pred_b, (float*)d_out);
}